// Round 2
// baseline (14275.009 us; speedup 1.0000x reference)
//
#include <hip/hip_runtime.h>
#include <hip/hip_bf16.h>
#include <math.h>

#define DEV __device__ __forceinline__

typedef unsigned short u16;
typedef __attribute__((ext_vector_type(8))) short s8v;   // 8 x bf16 (4 VGPRs)
typedef __attribute__((ext_vector_type(4))) float f4v;   // MFMA accumulator

// Problem constants
constexpr int NLAY = 8;
constexpr int SB   = 64 * 32;              // steps * batch = 2048 sequences

DEV float bf2f(u16 u) { unsigned x = ((unsigned)u) << 16; union { unsigned u; float f; } c; c.u = x; return c.f; }
DEV u16 f2bf(float f) { union { float f; unsigned u; } c; c.f = f; unsigned x = c.u; x += 0x7fffu + ((x >> 16) & 1u); return (u16)(x >> 16); }

DEV void load8bf(const u16* p, float* o) {
  uint4 q = *(const uint4*)p;
  o[0] = bf2f((u16)(q.x & 0xffff)); o[1] = bf2f((u16)(q.x >> 16));
  o[2] = bf2f((u16)(q.y & 0xffff)); o[3] = bf2f((u16)(q.y >> 16));
  o[4] = bf2f((u16)(q.z & 0xffff)); o[5] = bf2f((u16)(q.z >> 16));
  o[6] = bf2f((u16)(q.w & 0xffff)); o[7] = bf2f((u16)(q.w >> 16));
}
DEV void store8bf(u16* p, const float* v) {
  uint4 q;
  q.x = (unsigned)f2bf(v[0]) | ((unsigned)f2bf(v[1]) << 16);
  q.y = (unsigned)f2bf(v[2]) | ((unsigned)f2bf(v[3]) << 16);
  q.z = (unsigned)f2bf(v[4]) | ((unsigned)f2bf(v[5]) << 16);
  q.w = (unsigned)f2bf(v[6]) | ((unsigned)f2bf(v[7]) << 16);
  *(uint4*)p = q;
}

// async global->LDS, 16B per lane, LDS dest wave-uniform base + lane*16
DEV void cp16(const void* g, void* l) {
  __builtin_amdgcn_global_load_lds((const __attribute__((address_space(1))) unsigned*)g,
                                   (__attribute__((address_space(3))) unsigned*)l, 16, 0, 0);
}

// ---------------------------------------------------------------------------
// C[M,N] = A[M,K] @ Bt[N,K]^T + bias, bf16 in / bf16 out, fp32 accum.
// 128x128 tile, BK=64, 4 waves, 16x16x32 bf16 MFMA. All dims divisible.
// ---------------------------------------------------------------------------
template<int RELU>
__global__ __launch_bounds__(256) void gemm_bt(const u16* __restrict__ A, const u16* __restrict__ Bt,
                                               const float* __restrict__ bias, u16* __restrict__ C,
                                               int M, int N, int K) {
  __shared__ u16 As[128 * 64];
  __shared__ u16 Bs[128 * 64];
  const int tid = threadIdx.x, w = tid >> 6, lane = tid & 63;
  const int lrow = lane & 15, lquad = lane >> 4;
  const int m0 = blockIdx.y * 128, n0 = blockIdx.x * 128;
  const int wm = (w & 1) * 64, wn = (w >> 1) * 64;
  const int srow = lane >> 3, sch = (lane & 7) * 8;
  f4v acc[4][4] = {};
  for (int kt = 0; kt < K; kt += 64) {
    __syncthreads();
#pragma unroll
    for (int c = 0; c < 4; ++c) {
      int seg = w * 4 + c;  // 8 rows of the 128-row tile per call
      cp16(A + (size_t)(m0 + seg * 8 + srow) * K + kt + sch, &As[seg * 512]);
      cp16(Bt + (size_t)(n0 + seg * 8 + srow) * K + kt + sch, &Bs[seg * 512]);
    }
    __syncthreads();
#pragma unroll
    for (int kc = 0; kc < 2; ++kc) {
      s8v a[4], b[4];
#pragma unroll
      for (int t = 0; t < 4; ++t) {
        a[t] = *(const s8v*)&As[(wm + t * 16 + lrow) * 64 + kc * 32 + lquad * 8];
        b[t] = *(const s8v*)&Bs[(wn + t * 16 + lrow) * 64 + kc * 32 + lquad * 8];
      }
#pragma unroll
      for (int mt = 0; mt < 4; ++mt)
#pragma unroll
        for (int nt = 0; nt < 4; ++nt)
          acc[mt][nt] = __builtin_amdgcn_mfma_f32_16x16x32_bf16(a[mt], b[nt], acc[mt][nt], 0, 0, 0);
    }
  }
#pragma unroll
  for (int nt = 0; nt < 4; ++nt) {
    int col = n0 + wn + nt * 16 + lrow;
    float bv = bias[col];
#pragma unroll
    for (int mt = 0; mt < 4; ++mt) {
      size_t rbase = (size_t)(m0 + wm + mt * 16 + lquad * 4);
#pragma unroll
      for (int j = 0; j < 4; ++j) {
        float v = acc[mt][nt][j] + bv;
        if (RELU) v = fmaxf(v, 0.f);
        C[(rbase + j) * (size_t)N + col] = f2bf(v);
      }
    }
  }
}

// ---------------------------------------------------------------------------
// Self-attention: one block per (local step sl, batch b, head h). 64x64
// scores, key mask col <= s0+sl, softmax fp32, P@V. qkv local rows.
// ---------------------------------------------------------------------------
__global__ __launch_bounds__(256) void k_attn(const u16* __restrict__ qkv, u16* __restrict__ o, int s0) {
  const int h = blockIdx.x, b = blockIdx.y, sl = blockIdx.z;
  const int s = s0 + sl;
  __shared__ u16 qs[64][72], ks[64][72], vts[64][72], ps[64][72];
  const int tid = threadIdx.x;
  const int row = tid >> 2, c16 = (tid & 3) * 16;
  const size_t base = ((size_t)(sl * 32 + b) * 64) * 1536;
  {
    const u16* qp = qkv + base + (size_t)row * 1536 + h * 64 + c16;
    *(uint4*)&qs[row][c16]     = *(const uint4*)qp;
    *(uint4*)&qs[row][c16 + 8] = *(const uint4*)(qp + 8);
    *(uint4*)&ks[row][c16]     = *(const uint4*)(qp + 512);
    *(uint4*)&ks[row][c16 + 8] = *(const uint4*)(qp + 520);
    uint4 v0 = *(const uint4*)(qp + 1024), v1 = *(const uint4*)(qp + 1032);
    unsigned arr[8] = {v0.x, v0.y, v0.z, v0.w, v1.x, v1.y, v1.z, v1.w};
#pragma unroll
    for (int j = 0; j < 8; ++j) {  // transpose v into vts[d][l]
      vts[c16 + 2 * j][row]     = (u16)(arr[j] & 0xffff);
      vts[c16 + 2 * j + 1][row] = (u16)(arr[j] >> 16);
    }
  }
  __syncthreads();
  const int w = tid >> 6, lane = tid & 63, lrow = lane & 15, lquad = lane >> 4;
  f4v sc[4] = {};
  {
    s8v aq[2];
#pragma unroll
    for (int kc = 0; kc < 2; ++kc) aq[kc] = *(const s8v*)&qs[w * 16 + lrow][kc * 32 + lquad * 8];
#pragma unroll
    for (int nt = 0; nt < 4; ++nt)
#pragma unroll
      for (int kc = 0; kc < 2; ++kc) {
        s8v bk = *(const s8v*)&ks[nt * 16 + lrow][kc * 32 + lquad * 8];
        sc[nt] = __builtin_amdgcn_mfma_f32_16x16x32_bf16(aq[kc], bk, sc[nt], 0, 0, 0);
      }
  }
#pragma unroll
  for (int j = 0; j < 4; ++j) {  // per-row softmax (row = w*16 + lquad*4 + j)
    float v[4]; float mx = -3.0e38f;
#pragma unroll
    for (int nt = 0; nt < 4; ++nt) {
      int col = nt * 16 + lrow;
      float xx = sc[nt][j] * 0.125f;   // 1/sqrt(64)
      if (col > s) xx = -1e9f;         // key mask
      v[nt] = xx; mx = fmaxf(mx, xx);
    }
#pragma unroll
    for (int m = 1; m < 16; m <<= 1) mx = fmaxf(mx, __shfl_xor(mx, m));
    float sum = 0.f;
#pragma unroll
    for (int nt = 0; nt < 4; ++nt) { v[nt] = __expf(v[nt] - mx); sum += v[nt]; }
#pragma unroll
    for (int m = 1; m < 16; m <<= 1) sum += __shfl_xor(sum, m);
    float inv = 1.f / sum;
    int prow = w * 16 + lquad * 4 + j;
#pragma unroll
    for (int nt = 0; nt < 4; ++nt) ps[prow][nt * 16 + lrow] = f2bf(v[nt] * inv);
  }
  // P@V: ps rows are wave-local -> no barrier needed
  f4v oc[4] = {};
  {
    s8v ap[2];
#pragma unroll
    for (int kc = 0; kc < 2; ++kc) ap[kc] = *(const s8v*)&ps[w * 16 + lrow][kc * 32 + lquad * 8];
#pragma unroll
    for (int nt = 0; nt < 4; ++nt)
#pragma unroll
      for (int kc = 0; kc < 2; ++kc) {
        s8v bv = *(const s8v*)&vts[nt * 16 + lrow][kc * 32 + lquad * 8];
        oc[nt] = __builtin_amdgcn_mfma_f32_16x16x32_bf16(ap[kc], bv, oc[nt], 0, 0, 0);
      }
  }
  const size_t obase = (size_t)(sl * 32 + b) * 64;
#pragma unroll
  for (int nt = 0; nt < 4; ++nt) {
    int col = h * 64 + nt * 16 + lrow;
#pragma unroll
    for (int j = 0; j < 4; ++j) {
      int r = w * 16 + lquad * 4 + j;
      o[(obase + r) * 512 + col] = f2bf(oc[nt][j]);
    }
  }
}

// ---------------------------------------------------------------------------
// Residual + LN (and optionally +ca_add + second LN). One wave per 512-row.
// hb updated in place (bf16 stream), fp32 math. cab indexed by local seq.
// ---------------------------------------------------------------------------
template<int HAS2>
__global__ __launch_bounds__(256) void k_ln(u16* __restrict__ hb, const u16* __restrict__ tmpb,
                                            const u16* __restrict__ cab,
                                            const float* __restrict__ g1, const float* __restrict__ b1,
                                            const float* __restrict__ g2, const float* __restrict__ b2) {
  const int row = blockIdx.x * 4 + (threadIdx.x >> 6);
  const int lane = threadIdx.x & 63;
  const size_t off = (size_t)row * 512 + lane * 8;
  float hv[8], tv[8], t[8];
  load8bf(hb + off, hv); load8bf(tmpb + off, tv);
  float s = 0.f, ss = 0.f;
#pragma unroll
  for (int i = 0; i < 8; ++i) { t[i] = hv[i] + tv[i]; s += t[i]; ss += t[i] * t[i]; }
#pragma unroll
  for (int m = 1; m < 64; m <<= 1) { s += __shfl_xor(s, m); ss += __shfl_xor(ss, m); }
  float mean = s * (1.f / 512.f);
  float inv = 1.f / sqrtf(ss * (1.f / 512.f) - mean * mean + 1e-5f);
  float gv[8], bv[8];
  *(float4*)&gv[0] = *(const float4*)(g1 + lane * 8); *(float4*)&gv[4] = *(const float4*)(g1 + lane * 8 + 4);
  *(float4*)&bv[0] = *(const float4*)(b1 + lane * 8); *(float4*)&bv[4] = *(const float4*)(b1 + lane * 8 + 4);
  if (HAS2) {
    float cv[8]; load8bf(cab + (size_t)(row >> 6) * 512 + lane * 8, cv);
    float s2 = 0.f, ss2 = 0.f;
#pragma unroll
    for (int i = 0; i < 8; ++i) { float n = (t[i] - mean) * inv * gv[i] + bv[i] + cv[i]; t[i] = n; s2 += n; ss2 += n * n; }
#pragma unroll
    for (int m = 1; m < 64; m <<= 1) { s2 += __shfl_xor(s2, m); ss2 += __shfl_xor(ss2, m); }
    float mean2 = s2 * (1.f / 512.f);
    float inv2 = 1.f / sqrtf(ss2 * (1.f / 512.f) - mean2 * mean2 + 1e-5f);
    float g2v[8], b2v[8];
    *(float4*)&g2v[0] = *(const float4*)(g2 + lane * 8); *(float4*)&g2v[4] = *(const float4*)(g2 + lane * 8 + 4);
    *(float4*)&b2v[0] = *(const float4*)(b2 + lane * 8); *(float4*)&b2v[4] = *(const float4*)(b2 + lane * 8 + 4);
#pragma unroll
    for (int i = 0; i < 8; ++i) t[i] = (t[i] - mean2) * inv2 * g2v[i] + b2v[i];
  } else {
#pragma unroll
    for (int i = 0; i < 8; ++i) t[i] = (t[i] - mean) * inv * gv[i] + bv[i];
  }
  store8bf(hb + off, t);
}

// ---------------------------------------------------------------------------
// ctx0[b,l,:] = x_full[b,l] @ W_in + b_in + PE[l]   (B*L*D = 1M elements)
// ---------------------------------------------------------------------------
__global__ __launch_bounds__(256) void k_ctx(const float* __restrict__ x, const float* __restrict__ W_in,
                                             const float* __restrict__ b_in, u16* __restrict__ ctx0) {
  const int e = blockIdx.x * 256 + threadIdx.x;   // over B*L*D = 1M
  const int d = e & 511, l = (e >> 9) & 63, b = e >> 15;
  float acc = b_in[d];
  if (l > 0) {
    const float* xr = x + (size_t)(b * 64 + l - 1) * 32;
#pragma unroll 8
    for (int z = 0; z < 32; ++z) acc += xr[z] * W_in[z * 512 + d];
  }
  const float dv = __expf(-9.210340371976184f * (float)(d & ~1) * (1.f / 512.f));
  const float ang = (float)l * dv;
  acc += (d & 1) ? cosf(ang) : sinf(ang);
  ctx0[(size_t)e] = f2bf(acc);
}

// ---------------------------------------------------------------------------
// Replicate ctx0 (B,L,D) into hb_c for S steps: hb_c[(sl*32+b)*64+l] = ctx0[b,l]
// Each thread copies 8 elements.
// ---------------------------------------------------------------------------
__global__ __launch_bounds__(256) void k_rep(const u16* __restrict__ ctx0, u16* __restrict__ hb) {
  const size_t e = (size_t)blockIdx.x * 256 + threadIdx.x;  // over rows*64
  const int d8 = (int)(e & 63);
  const size_t row = e >> 6;
  const int l = (int)(row & 63);
  const int b = (int)((row >> 6) & 31);
  *(uint4*)(hb + row * 512 + d8 * 8) = *(const uint4*)(ctx0 + ((size_t)(b * 64 + l) * 512) + d8 * 8);
}

// ---------------------------------------------------------------------------
// VQ nearest-neighbor (argmin over 8192 codes, first-min tiebreak) fused with
// mem_h = codebook[kmin] @ W_in + b_in. One block per (step s, batch b).
// ---------------------------------------------------------------------------
__global__ __launch_bounds__(256) void k_vq(const float* __restrict__ x, const float* __restrict__ cb,
                                            const float* __restrict__ W_in, const float* __restrict__ b_in,
                                            u16* __restrict__ memh) {
  const int tok = blockIdx.x;              // = s*32 + b
  const int s = tok >> 5, b = tok & 31;
  const int tid = threadIdx.x;
  __shared__ float xs[32], cs[32];
  __shared__ float rd[256]; __shared__ int ri[256];
  if (tid < 32) xs[tid] = x[(size_t)(b * 64 + s) * 32 + tid];  // mem token = x[b, s]
  __syncthreads();
  float bd = 3.0e38f; int bi = 0;
  for (int c = tid; c < 8192; c += 256) {
    const float4* cr = (const float4*)(cb + (size_t)c * 32);
    float d = 0.f;
#pragma unroll
    for (int z4 = 0; z4 < 8; ++z4) {
      float4 cv = cr[z4];
      float d0 = xs[z4 * 4 + 0] - cv.x, d1 = xs[z4 * 4 + 1] - cv.y;
      float d2 = xs[z4 * 4 + 2] - cv.z, d3 = xs[z4 * 4 + 3] - cv.w;
      d += d0 * d0 + d1 * d1 + d2 * d2 + d3 * d3;
    }
    if (d < bd) { bd = d; bi = c; }
  }
  rd[tid] = bd; ri[tid] = bi;
  __syncthreads();
  for (int st = 128; st > 0; st >>= 1) {
    if (tid < st) {
      float dn = rd[tid + st]; int in2 = ri[tid + st];
      if (dn < rd[tid] || (dn == rd[tid] && in2 < ri[tid])) { rd[tid] = dn; ri[tid] = in2; }
    }
    __syncthreads();
  }
  const int kmin = ri[0];
  if (tid < 32) cs[tid] = cb[(size_t)kmin * 32 + tid];
  __syncthreads();
  for (int o = tid; o < 512; o += 256) {
    float a = b_in[o];
#pragma unroll 8
    for (int z = 0; z < 32; ++z) a += cs[z] * W_in[z * 512 + o];
    memh[(size_t)tok * 512 + o] = f2bf(a);
  }
}

// ---------------------------------------------------------------------------
// Final: out[b,s,:] = LN(hb_c[local seq, l=s, :]) @ W_out + b_out.
// One 64-thread block per local (sl,b). s = s0 + sl.
// ---------------------------------------------------------------------------
__global__ __launch_bounds__(64) void k_final(const u16* __restrict__ hb, const float* __restrict__ g,
                                              const float* __restrict__ bta, const float* __restrict__ Wout,
                                              const float* __restrict__ bout, float* __restrict__ out, int s0) {
  const int blk = blockIdx.x;            // local seq = sl*32 + b
  const int s = s0 + (blk >> 5), b = blk & 31;
  const int lane = threadIdx.x;
  __shared__ float ns[512];
  const size_t roff = ((size_t)blk * 64 + s) * 512;
  float v[8]; load8bf(hb + roff + lane * 8, v);
  float sm = 0.f, ssm = 0.f;
#pragma unroll
  for (int i = 0; i < 8; ++i) { sm += v[i]; ssm += v[i] * v[i]; }
#pragma unroll
  for (int m = 1; m < 64; m <<= 1) { sm += __shfl_xor(sm, m); ssm += __shfl_xor(ssm, m); }
  float mean = sm * (1.f / 512.f);
  float inv = 1.f / sqrtf(ssm * (1.f / 512.f) - mean * mean + 1e-5f);
#pragma unroll
  for (int i = 0; i < 8; ++i) ns[lane * 8 + i] = (v[i] - mean) * inv * g[lane * 8 + i] + bta[lane * 8 + i];
  __syncthreads();
  const int col = lane & 31, half = lane >> 5;
  float a = 0.f;
  for (int k = half * 256; k < half * 256 + 256; ++k) a += ns[k] * Wout[(size_t)k * 32 + col];
  a += __shfl_xor(a, 32);
  if (lane < 32) out[((size_t)b * 64 + s) * 32 + col] = a + bout[col];
}

// ---------------------------------------------------------------------------
// Transpose + fp32->bf16 cast of weights (batched over NL via blockIdx.z):
// dst[l][c][r] = src[l][r][col0 + c]
// ---------------------------------------------------------------------------
__global__ void k_tcast(const float* __restrict__ src, u16* __restrict__ dst, int R, int C, int ld, int col0) {
  const int l = blockIdx.z;
  src += (size_t)l * R * ld;
  dst += (size_t)l * R * C;
  __shared__ float t[32][33];
  const int c0 = blockIdx.x * 32, r0 = blockIdx.y * 32;
  const int tx = threadIdx.x, ty = threadIdx.y;
#pragma unroll
  for (int k = 0; k < 4; ++k)
    t[ty + 8 * k][tx] = src[(size_t)(r0 + ty + 8 * k) * ld + col0 + c0 + tx];
  __syncthreads();
#pragma unroll
  for (int k = 0; k < 4; ++k)
    dst[(size_t)(c0 + ty + 8 * k) * R + r0 + tx] = f2bf(t[tx][ty + 8 * k]);
}

// ---------------------------------------------------------------------------
extern "C" void kernel_launch(void* const* d_in, const int* in_sizes, int n_in,
                              void* d_out, int out_size, void* d_ws, size_t ws_size,
                              hipStream_t stream) {
  (void)in_sizes; (void)n_in; (void)out_size;
  const float* x    = (const float*)d_in[0];
  const float* cb   = (const float*)d_in[1];
  const float* W_in = (const float*)d_in[2];
  const float* b_in = (const float*)d_in[3];
  const float* saqw = (const float*)d_in[4];
  const float* saqb = (const float*)d_in[5];
  const float* saow = (const float*)d_in[6];
  const float* saob = (const float*)d_in[7];
  const float* caqw = (const float*)d_in[8];
  const float* caqb = (const float*)d_in[9];
  const float* caow = (const float*)d_in[10];
  const float* caob = (const float*)d_in[11];
  const float* f1w  = (const float*)d_in[12];
  const float* f1b  = (const float*)d_in[13];
  const float* f2w  = (const float*)d_in[14];
  const float* f2b  = (const float*)d_in[15];
  const float* l1g  = (const float*)d_in[16];
  const float* l1b  = (const float*)d_in[17];
  const float* l2g  = (const float*)d_in[18];
  const float* l2b  = (const float*)d_in[19];
  const float* l3g  = (const float*)d_in[20];
  const float* l3b  = (const float*)d_in[21];
  const float* lng  = (const float*)d_in[22];
  const float* lnb  = (const float*)d_in[23];
  const float* Wout = (const float*)d_in[24];
  const float* bout = (const float*)d_in[25];
  float* out = (float*)d_out;

  // -------------------- workspace layout (u16 elements) --------------------
  u16* ws = (u16*)d_ws;
  size_t off = 0;
  auto alloc = [&](size_t n) { u16* p = ws + off; off += n; return p; };
  // persistent region (~82 MB)
  u16* ctx0  = alloc((size_t)32 * 64 * 512);          // 1,048,576
  u16* cabuf = alloc((size_t)NLAY * SB * 512);        // 8,388,608
  u16* memh  = alloc((size_t)SB * 512);               // 1,048,576
  u16* tmpv  = alloc((size_t)SB * 512);               // 1,048,576
  u16* wqkvT = alloc((size_t)NLAY * 1536 * 512);      // 6,291,456
  u16* woutT = alloc((size_t)NLAY * 512 * 512);       // 2,097,152
  u16* wf1T  = alloc((size_t)NLAY * 2048 * 512);      // 8,388,608
  u16* wf2T  = alloc((size_t)NLAY * 512 * 2048);      // 8,388,608
  u16* wcavT = alloc((size_t)NLAY * 512 * 512);       // 2,097,152
  u16* wcaoT = alloc((size_t)NLAY * 512 * 512);       // 2,097,152
  const size_t persist = off;                          // 40,894,464 el

  // chunked over steps: S steps/chunk; per-chunk footprint = S * 6,291,456 el
  int S = 16;
  while (S > 1 && (persist + (size_t)S * 6291456ull) * 2 > ws_size) S >>= 1;
  const int nchunk = 64 / S;
  const size_t rows_c = (size_t)S * 2048;              // rows per chunk

  u16* hb   = alloc(rows_c * 512);    // residual stream for the chunk
  u16* regA = alloc(rows_c * 2048);   // qkv (1536) + attn-out (512) / ffn-mid (2048)
  u16* tmpb = alloc(rows_c * 512);    // GEMM output scratch
  u16* qkvb = regA;                   // [rows_c][1536]
  u16* attb = regA + rows_c * 1536;   // [rows_c][512]
  u16* midb = regA;                   // [rows_c][2048]

  // -------------------- weight transpose + cast (every launch) -------------
  dim3 tb(32, 8);
  k_tcast<<<dim3(48, 16, 8), tb, 0, stream>>>(saqw, wqkvT, 512, 1536, 1536, 0);
  k_tcast<<<dim3(16, 16, 8), tb, 0, stream>>>(saow, woutT, 512, 512, 512, 0);
  k_tcast<<<dim3(64, 16, 8), tb, 0, stream>>>(f1w, wf1T, 512, 2048, 2048, 0);
  k_tcast<<<dim3(16, 64, 8), tb, 0, stream>>>(f2w, wf2T, 2048, 512, 512, 0);
  k_tcast<<<dim3(16, 16, 8), tb, 0, stream>>>(caqw, wcavT, 512, 512, 1536, 1024);  // v-slice of ca qkv
  k_tcast<<<dim3(16, 16, 8), tb, 0, stream>>>(caow, wcaoT, 512, 512, 512, 0);

  k_ctx<<<4096, 256, 0, stream>>>(x, W_in, b_in, ctx0);
  k_vq<<<2048, 256, 0, stream>>>(x, cb, W_in, b_in, memh);

  // Cross-attention collapses to a per-(s,b) constant: (mem_h@Wv+bv)@Wout+bout
  for (int l = 0; l < NLAY; ++l) {
    gemm_bt<0><<<dim3(4, 16), 256, 0, stream>>>(memh, wcavT + (size_t)l * 512 * 512,
                                                caqb + (size_t)l * 1536 + 1024, tmpv, SB, 512, 512);
    gemm_bt<0><<<dim3(4, 16), 256, 0, stream>>>(tmpv, wcaoT + (size_t)l * 512 * 512,
                                                caob + (size_t)l * 512, cabuf + (size_t)l * SB * 512, SB, 512, 512);
  }

  // -------------------- main decoder, chunked over steps --------------------
  const int mg = (int)(rows_c / 128);   // GEMM grid rows
  for (int c = 0; c < nchunk; ++c) {
    const int s0 = c * S;
    k_rep<<<(int)(rows_c * 64 / 256), 256, 0, stream>>>(ctx0, hb);
    for (int l = 0; l < NLAY; ++l) {
      gemm_bt<0><<<dim3(12, mg), 256, 0, stream>>>(hb, wqkvT + (size_t)l * 1536 * 512,
                                                   saqb + (size_t)l * 1536, qkvb, (int)rows_c, 1536, 512);
      k_attn<<<dim3(8, 32, S), 256, 0, stream>>>(qkvb, attb, s0);
      gemm_bt<0><<<dim3(4, mg), 256, 0, stream>>>(attb, woutT + (size_t)l * 512 * 512,
                                                  saob + (size_t)l * 512, tmpb, (int)rows_c, 512, 512);
      k_ln<1><<<(int)(rows_c / 4), 256, 0, stream>>>(hb, tmpb,
                                                     cabuf + ((size_t)l * SB + (size_t)s0 * 32) * 512,
                                                     l1g + l * 512, l1b + l * 512, l2g + l * 512, l2b + l * 512);
      gemm_bt<1><<<dim3(16, mg), 256, 0, stream>>>(hb, wf1T + (size_t)l * 2048 * 512,
                                                   f1b + (size_t)l * 2048, midb, (int)rows_c, 2048, 512);
      gemm_bt<0><<<dim3(4, mg), 256, 0, stream>>>(midb, wf2T + (size_t)l * 512 * 2048,
                                                  f2b + (size_t)l * 512, tmpb, (int)rows_c, 512, 2048);
      k_ln<0><<<(int)(rows_c / 4), 256, 0, stream>>>(hb, tmpb, nullptr,
                                                     l3g + l * 512, l3b + l * 512, nullptr, nullptr);
    }
    k_final<<<S * 32, 64, 0, stream>>>(hb, lng, lnb, Wout, bout, out, s0);
  }
}

// Round 3
// 8104.230 us; speedup vs baseline: 1.7614x; 1.7614x over previous
//
#include <hip/hip_runtime.h>
#include <hip/hip_bf16.h>
#include <math.h>

#define DEV __device__ __forceinline__

typedef unsigned short u16;
typedef __attribute__((ext_vector_type(8))) short s8v;   // 8 x bf16 (4 VGPRs)
typedef __attribute__((ext_vector_type(4))) float f4v;   // MFMA accumulator

// Problem constants
constexpr int NLAY = 8;
constexpr int SB   = 64 * 32;                 // steps * batch = 2048 sequences
constexpr size_t RAGG = 66560;                // 32 * sum_{s=0}^{63}(s+1) = 520*128

DEV float bf2f(u16 u) { unsigned x = ((unsigned)u) << 16; union { unsigned u; float f; } c; c.u = x; return c.f; }
DEV u16 f2bf(float f) { union { float f; unsigned u; } c; c.f = f; unsigned x = c.u; x += 0x7fffu + ((x >> 16) & 1u); return (u16)(x >> 16); }

DEV void load8bf(const u16* p, float* o) {
  uint4 q = *(const uint4*)p;
  o[0] = bf2f((u16)(q.x & 0xffff)); o[1] = bf2f((u16)(q.x >> 16));
  o[2] = bf2f((u16)(q.y & 0xffff)); o[3] = bf2f((u16)(q.y >> 16));
  o[4] = bf2f((u16)(q.z & 0xffff)); o[5] = bf2f((u16)(q.z >> 16));
  o[6] = bf2f((u16)(q.w & 0xffff)); o[7] = bf2f((u16)(q.w >> 16));
}
DEV void store8bf(u16* p, const float* v) {
  uint4 q;
  q.x = (unsigned)f2bf(v[0]) | ((unsigned)f2bf(v[1]) << 16);
  q.y = (unsigned)f2bf(v[2]) | ((unsigned)f2bf(v[3]) << 16);
  q.z = (unsigned)f2bf(v[4]) | ((unsigned)f2bf(v[5]) << 16);
  q.w = (unsigned)f2bf(v[6]) | ((unsigned)f2bf(v[7]) << 16);
  *(uint4*)p = q;
}

// ragged row offset of sequence (s, b): rows 0..s live at [soff, soff+s]
DEV size_t seqoff(int s, int b) { return (size_t)16 * s * (s + 1) + (size_t)b * (s + 1); }

// async global->LDS, 16B per lane, LDS dest wave-uniform base + lane*16
DEV void cp16(const void* g, void* l) {
  __builtin_amdgcn_global_load_lds((const __attribute__((address_space(1))) unsigned*)g,
                                   (__attribute__((address_space(3))) unsigned*)l, 16, 0, 0);
}

// ---------------------------------------------------------------------------
// C[M,N] = A[M,K] @ Bt[N,K]^T + bias, bf16 in / bf16 out, fp32 accum.
// 128x128 tile, BK=64, 4 waves, 16x16x32 bf16 MFMA. M,N,K divisible.
// ---------------------------------------------------------------------------
template<int RELU>
__global__ __launch_bounds__(256) void gemm_bt(const u16* __restrict__ A, const u16* __restrict__ Bt,
                                               const float* __restrict__ bias, u16* __restrict__ C,
                                               int N, int K) {
  __shared__ u16 As[128 * 64];
  __shared__ u16 Bs[128 * 64];
  const int tid = threadIdx.x, w = tid >> 6, lane = tid & 63;
  const int lrow = lane & 15, lquad = lane >> 4;
  const int m0 = blockIdx.y * 128, n0 = blockIdx.x * 128;
  const int wm = (w & 1) * 64, wn = (w >> 1) * 64;
  const int srow = lane >> 3, sch = (lane & 7) * 8;
  f4v acc[4][4] = {};
  for (int kt = 0; kt < K; kt += 64) {
    __syncthreads();
#pragma unroll
    for (int c = 0; c < 4; ++c) {
      int seg = w * 4 + c;  // 8 rows of the 128-row tile per call
      cp16(A + (size_t)(m0 + seg * 8 + srow) * K + kt + sch, &As[seg * 512]);
      cp16(Bt + (size_t)(n0 + seg * 8 + srow) * K + kt + sch, &Bs[seg * 512]);
    }
    __syncthreads();
#pragma unroll
    for (int kc = 0; kc < 2; ++kc) {
      s8v a[4], b[4];
#pragma unroll
      for (int t = 0; t < 4; ++t) {
        a[t] = *(const s8v*)&As[(wm + t * 16 + lrow) * 64 + kc * 32 + lquad * 8];
        b[t] = *(const s8v*)&Bs[(wn + t * 16 + lrow) * 64 + kc * 32 + lquad * 8];
      }
#pragma unroll
      for (int mt = 0; mt < 4; ++mt)
#pragma unroll
        for (int nt = 0; nt < 4; ++nt)
          acc[mt][nt] = __builtin_amdgcn_mfma_f32_16x16x32_bf16(a[mt], b[nt], acc[mt][nt], 0, 0, 0);
    }
  }
#pragma unroll
  for (int nt = 0; nt < 4; ++nt) {
    int col = n0 + wn + nt * 16 + lrow;
    float bv = bias[col];
#pragma unroll
    for (int mt = 0; mt < 4; ++mt) {
      size_t rbase = (size_t)(m0 + wm + mt * 16 + lquad * 4);
#pragma unroll
      for (int j = 0; j < 4; ++j) {
        float v = acc[mt][nt][j] + bv;
        if (RELU) v = fmaxf(v, 0.f);
        C[(rbase + j) * (size_t)N + col] = f2bf(v);
      }
    }
  }
}

// ---------------------------------------------------------------------------
// Self-attention on ragged rows: block per (h, b, local step). Sequence
// (s=sbase+sl, b) has s+1 valid rows at soff(s,b)-row0 in the chunk buffers.
// Staging reads clamp row to <= s; keys > s are masked; only rows <= s are
// written back.
// ---------------------------------------------------------------------------
__global__ __launch_bounds__(256) void k_attn(const u16* __restrict__ qkv, u16* __restrict__ o,
                                              int sbase, size_t row0) {
  const int h = blockIdx.x, b = blockIdx.y, sl = blockIdx.z;
  const int s = sbase + sl;
  const size_t soff = seqoff(s, b) - row0;
  __shared__ u16 qs[64][72], ks[64][72], vts[64][72], ps[64][72];
  const int tid = threadIdx.x;
  const int row = tid >> 2, c16 = (tid & 3) * 16;
  const int rcl = row <= s ? row : s;
  {
    const u16* qp = qkv + (soff + rcl) * 1536 + h * 64 + c16;
    *(uint4*)&qs[row][c16]     = *(const uint4*)qp;
    *(uint4*)&qs[row][c16 + 8] = *(const uint4*)(qp + 8);
    *(uint4*)&ks[row][c16]     = *(const uint4*)(qp + 512);
    *(uint4*)&ks[row][c16 + 8] = *(const uint4*)(qp + 520);
    uint4 v0 = *(const uint4*)(qp + 1024), v1 = *(const uint4*)(qp + 1032);
    unsigned arr[8] = {v0.x, v0.y, v0.z, v0.w, v1.x, v1.y, v1.z, v1.w};
#pragma unroll
    for (int j = 0; j < 8; ++j) {  // transpose v into vts[d][l]
      vts[c16 + 2 * j][row]     = (u16)(arr[j] & 0xffff);
      vts[c16 + 2 * j + 1][row] = (u16)(arr[j] >> 16);
    }
  }
  __syncthreads();
  const int w = tid >> 6, lane = tid & 63, lrow = lane & 15, lquad = lane >> 4;
  f4v sc[4] = {};
  {
    s8v aq[2];
#pragma unroll
    for (int kc = 0; kc < 2; ++kc) aq[kc] = *(const s8v*)&qs[w * 16 + lrow][kc * 32 + lquad * 8];
#pragma unroll
    for (int nt = 0; nt < 4; ++nt)
#pragma unroll
      for (int kc = 0; kc < 2; ++kc) {
        s8v bk = *(const s8v*)&ks[nt * 16 + lrow][kc * 32 + lquad * 8];
        sc[nt] = __builtin_amdgcn_mfma_f32_16x16x32_bf16(aq[kc], bk, sc[nt], 0, 0, 0);
      }
  }
#pragma unroll
  for (int j = 0; j < 4; ++j) {  // per-row softmax (row = w*16 + lquad*4 + j)
    float v[4]; float mx = -3.0e38f;
#pragma unroll
    for (int nt = 0; nt < 4; ++nt) {
      int col = nt * 16 + lrow;
      float xx = sc[nt][j] * 0.125f;   // 1/sqrt(64)
      if (col > s) xx = -1e9f;         // key mask
      v[nt] = xx; mx = fmaxf(mx, xx);
    }
#pragma unroll
    for (int m = 1; m < 16; m <<= 1) mx = fmaxf(mx, __shfl_xor(mx, m));
    float sum = 0.f;
#pragma unroll
    for (int nt = 0; nt < 4; ++nt) { v[nt] = __expf(v[nt] - mx); sum += v[nt]; }
#pragma unroll
    for (int m = 1; m < 16; m <<= 1) sum += __shfl_xor(sum, m);
    float inv = 1.f / sum;
    int prow = w * 16 + lquad * 4 + j;
#pragma unroll
    for (int nt = 0; nt < 4; ++nt) ps[prow][nt * 16 + lrow] = f2bf(v[nt] * inv);
  }
  // P@V: ps rows are wave-local -> no barrier needed
  f4v oc[4] = {};
  {
    s8v ap[2];
#pragma unroll
    for (int kc = 0; kc < 2; ++kc) ap[kc] = *(const s8v*)&ps[w * 16 + lrow][kc * 32 + lquad * 8];
#pragma unroll
    for (int nt = 0; nt < 4; ++nt)
#pragma unroll
      for (int kc = 0; kc < 2; ++kc) {
        s8v bv = *(const s8v*)&vts[nt * 16 + lrow][kc * 32 + lquad * 8];
        oc[nt] = __builtin_amdgcn_mfma_f32_16x16x32_bf16(ap[kc], bv, oc[nt], 0, 0, 0);
      }
  }
#pragma unroll
  for (int nt = 0; nt < 4; ++nt) {
    int col = h * 64 + nt * 16 + lrow;
#pragma unroll
    for (int j = 0; j < 4; ++j) {
      int r = w * 16 + lquad * 4 + j;
      if (r <= s) o[(soff + r) * 512 + col] = f2bf(oc[nt][j]);
    }
  }
}

// ---------------------------------------------------------------------------
// Residual + LN (and optionally +ca_add + second LN). One wave per 512-row.
// hb updated in place. cab (layer's CA constant) indexed via row->seq map.
// ---------------------------------------------------------------------------
template<int HAS2>
__global__ __launch_bounds__(256) void k_ln(u16* __restrict__ hb, const u16* __restrict__ tmpb,
                                            const u16* __restrict__ cab, const int* __restrict__ map,
                                            size_t row0,
                                            const float* __restrict__ g1, const float* __restrict__ b1,
                                            const float* __restrict__ g2, const float* __restrict__ b2) {
  const int row = blockIdx.x * 4 + (threadIdx.x >> 6);
  const int lane = threadIdx.x & 63;
  const size_t off = (size_t)row * 512 + lane * 8;
  float hv[8], tv[8], t[8];
  load8bf(hb + off, hv); load8bf(tmpb + off, tv);
  float s = 0.f, ss = 0.f;
#pragma unroll
  for (int i = 0; i < 8; ++i) { t[i] = hv[i] + tv[i]; s += t[i]; ss += t[i] * t[i]; }
#pragma unroll
  for (int m = 1; m < 64; m <<= 1) { s += __shfl_xor(s, m); ss += __shfl_xor(ss, m); }
  float mean = s * (1.f / 512.f);
  float inv = 1.f / sqrtf(ss * (1.f / 512.f) - mean * mean + 1e-5f);
  float gv[8], bv[8];
  *(float4*)&gv[0] = *(const float4*)(g1 + lane * 8); *(float4*)&gv[4] = *(const float4*)(g1 + lane * 8 + 4);
  *(float4*)&bv[0] = *(const float4*)(b1 + lane * 8); *(float4*)&bv[4] = *(const float4*)(b1 + lane * 8 + 4);
  if (HAS2) {
    const int seq = map[row0 + row];
    float cv[8]; load8bf(cab + (size_t)seq * 512 + lane * 8, cv);
    float s2 = 0.f, ss2 = 0.f;
#pragma unroll
    for (int i = 0; i < 8; ++i) { float n = (t[i] - mean) * inv * gv[i] + bv[i] + cv[i]; t[i] = n; s2 += n; ss2 += n * n; }
#pragma unroll
    for (int m = 1; m < 64; m <<= 1) { s2 += __shfl_xor(s2, m); ss2 += __shfl_xor(ss2, m); }
    float mean2 = s2 * (1.f / 512.f);
    float inv2 = 1.f / sqrtf(ss2 * (1.f / 512.f) - mean2 * mean2 + 1e-5f);
    float g2v[8], b2v[8];
    *(float4*)&g2v[0] = *(const float4*)(g2 + lane * 8); *(float4*)&g2v[4] = *(const float4*)(g2 + lane * 8 + 4);
    *(float4*)&b2v[0] = *(const float4*)(b2 + lane * 8); *(float4*)&b2v[4] = *(const float4*)(b2 + lane * 8 + 4);
#pragma unroll
    for (int i = 0; i < 8; ++i) t[i] = (t[i] - mean2) * inv2 * g2v[i] + b2v[i];
  } else {
#pragma unroll
    for (int i = 0; i < 8; ++i) t[i] = (t[i] - mean) * inv * gv[i] + bv[i];
  }
  store8bf(hb + off, t);
}

// ---------------------------------------------------------------------------
// ctx0[b,l,:] = x_full[b,l] @ W_in + b_in + PE[l]   (B*L*D = 1M elements)
// ---------------------------------------------------------------------------
__global__ __launch_bounds__(256) void k_ctx(const float* __restrict__ x, const float* __restrict__ W_in,
                                             const float* __restrict__ b_in, u16* __restrict__ ctx0) {
  const int e = blockIdx.x * 256 + threadIdx.x;   // over B*L*D = 1M
  const int d = e & 511, l = (e >> 9) & 63, b = e >> 15;
  float acc = b_in[d];
  if (l > 0) {
    const float* xr = x + (size_t)(b * 64 + l - 1) * 32;
#pragma unroll 8
    for (int z = 0; z < 32; ++z) acc += xr[z] * W_in[z * 512 + d];
  }
  const float dv = __expf(-9.210340371976184f * (float)(d & ~1) * (1.f / 512.f));
  const float ang = (float)l * dv;
  acc += (d & 1) ? cosf(ang) : sinf(ang);
  ctx0[(size_t)e] = f2bf(acc);
}

// ---------------------------------------------------------------------------
// Fill ragged row -> seq map. One 64-thread block per (s,b) sequence.
// ---------------------------------------------------------------------------
__global__ __launch_bounds__(64) void k_map(int* __restrict__ map) {
  const int seq = blockIdx.x;           // s*32 + b
  const int s = seq >> 5, b = seq & 31;
  const int l = threadIdx.x;
  if (l <= s) map[seqoff(s, b) + l] = seq;
}

// ---------------------------------------------------------------------------
// Replicate ctx0 into the chunk's ragged residual stream:
// hb[seqoff(s,b)-row0 + l] = ctx0[b,l] for l <= s. Block per (sl,b).
// ---------------------------------------------------------------------------
__global__ __launch_bounds__(256) void k_rep(const u16* __restrict__ ctx0, u16* __restrict__ hb,
                                             int sbase, size_t row0) {
  const int sl = blockIdx.x >> 5, b = blockIdx.x & 31;
  const int s = sbase + sl;
  const size_t dst0 = seqoff(s, b) - row0;
  const int tid = threadIdx.x;
  for (int idx = tid; idx < (s + 1) * 64; idx += 256) {
    const int l = idx >> 6, d8 = idx & 63;
    *(uint4*)(hb + (dst0 + l) * 512 + d8 * 8) =
        *(const uint4*)(ctx0 + ((size_t)(b * 64 + l) * 512) + d8 * 8);
  }
}

// ---------------------------------------------------------------------------
// VQ nearest-neighbor (argmin over 8192 codes, first-min tiebreak) fused with
// mem_h = codebook[kmin] @ W_in + b_in. One block per (step s, batch b).
// ---------------------------------------------------------------------------
__global__ __launch_bounds__(256) void k_vq(const float* __restrict__ x, const float* __restrict__ cb,
                                            const float* __restrict__ W_in, const float* __restrict__ b_in,
                                            u16* __restrict__ memh) {
  const int tok = blockIdx.x;              // = s*32 + b
  const int s = tok >> 5, b = tok & 31;
  const int tid = threadIdx.x;
  __shared__ float xs[32], cs[32];
  __shared__ float rd[256]; __shared__ int ri[256];
  if (tid < 32) xs[tid] = x[(size_t)(b * 64 + s) * 32 + tid];  // mem token = x[b, s]
  __syncthreads();
  float bd = 3.0e38f; int bi = 0;
  for (int c = tid; c < 8192; c += 256) {
    const float4* cr = (const float4*)(cb + (size_t)c * 32);
    float d = 0.f;
#pragma unroll
    for (int z4 = 0; z4 < 8; ++z4) {
      float4 cv = cr[z4];
      float d0 = xs[z4 * 4 + 0] - cv.x, d1 = xs[z4 * 4 + 1] - cv.y;
      float d2 = xs[z4 * 4 + 2] - cv.z, d3 = xs[z4 * 4 + 3] - cv.w;
      d += d0 * d0 + d1 * d1 + d2 * d2 + d3 * d3;
    }
    if (d < bd) { bd = d; bi = c; }
  }
  rd[tid] = bd; ri[tid] = bi;
  __syncthreads();
  for (int st = 128; st > 0; st >>= 1) {
    if (tid < st) {
      float dn = rd[tid + st]; int in2 = ri[tid + st];
      if (dn < rd[tid] || (dn == rd[tid] && in2 < ri[tid])) { rd[tid] = dn; ri[tid] = in2; }
    }
    __syncthreads();
  }
  const int kmin = ri[0];
  if (tid < 32) cs[tid] = cb[(size_t)kmin * 32 + tid];
  __syncthreads();
  for (int o = tid; o < 512; o += 256) {
    float a = b_in[o];
#pragma unroll 8
    for (int z = 0; z < 32; ++z) a += cs[z] * W_in[z * 512 + o];
    memh[(size_t)tok * 512 + o] = f2bf(a);
  }
}

// ---------------------------------------------------------------------------
// Final: out[b,s,:] = LN(hb[seqoff(s,b)-row0 + s, :]) @ W_out + b_out.
// One 64-thread block per (sl,b).
// ---------------------------------------------------------------------------
__global__ __launch_bounds__(64) void k_final(const u16* __restrict__ hb, const float* __restrict__ g,
                                              const float* __restrict__ bta, const float* __restrict__ Wout,
                                              const float* __restrict__ bout, float* __restrict__ out,
                                              int sbase, size_t row0) {
  const int blk = blockIdx.x;            // sl*32 + b
  const int s = sbase + (blk >> 5), b = blk & 31;
  const int lane = threadIdx.x;
  __shared__ float ns[512];
  const size_t roff = (seqoff(s, b) - row0 + s) * 512;
  float v[8]; load8bf(hb + roff + lane * 8, v);
  float sm = 0.f, ssm = 0.f;
#pragma unroll
  for (int i = 0; i < 8; ++i) { sm += v[i]; ssm += v[i] * v[i]; }
#pragma unroll
  for (int m = 1; m < 64; m <<= 1) { sm += __shfl_xor(sm, m); ssm += __shfl_xor(ssm, m); }
  float mean = sm * (1.f / 512.f);
  float inv = 1.f / sqrtf(ssm * (1.f / 512.f) - mean * mean + 1e-5f);
#pragma unroll
  for (int i = 0; i < 8; ++i) ns[lane * 8 + i] = (v[i] - mean) * inv * g[lane * 8 + i] + bta[lane * 8 + i];
  __syncthreads();
  const int col = lane & 31, half = lane >> 5;
  float a = 0.f;
  for (int k = half * 256; k < half * 256 + 256; ++k) a += ns[k] * Wout[(size_t)k * 32 + col];
  a += __shfl_xor(a, 32);
  if (lane < 32) out[((size_t)b * 64 + s) * 32 + col] = a + bout[col];
}

// ---------------------------------------------------------------------------
// Transpose + fp32->bf16 cast of weights (batched over NL via blockIdx.z):
// dst[l][c][r] = src[l][r][col0 + c]
// ---------------------------------------------------------------------------
__global__ void k_tcast(const float* __restrict__ src, u16* __restrict__ dst, int R, int C, int ld, int col0) {
  const int l = blockIdx.z;
  src += (size_t)l * R * ld;
  dst += (size_t)l * R * C;
  __shared__ float t[32][33];
  const int c0 = blockIdx.x * 32, r0 = blockIdx.y * 32;
  const int tx = threadIdx.x, ty = threadIdx.y;
#pragma unroll
  for (int k = 0; k < 4; ++k)
    t[ty + 8 * k][tx] = src[(size_t)(r0 + ty + 8 * k) * ld + col0 + c0 + tx];
  __syncthreads();
#pragma unroll
  for (int k = 0; k < 4; ++k)
    dst[(size_t)(c0 + ty + 8 * k) * R + r0 + tx] = f2bf(t[tx][ty + 8 * k]);
}

// ---------------------------------------------------------------------------
extern "C" void kernel_launch(void* const* d_in, const int* in_sizes, int n_in,
                              void* d_out, int out_size, void* d_ws, size_t ws_size,
                              hipStream_t stream) {
  (void)in_sizes; (void)n_in; (void)out_size;
  const float* x    = (const float*)d_in[0];
  const float* cb   = (const float*)d_in[1];
  const float* W_in = (const float*)d_in[2];
  const float* b_in = (const float*)d_in[3];
  const float* saqw = (const float*)d_in[4];
  const float* saqb = (const float*)d_in[5];
  const float* saow = (const float*)d_in[6];
  const float* saob = (const float*)d_in[7];
  const float* caqw = (const float*)d_in[8];
  const float* caqb = (const float*)d_in[9];
  const float* caow = (const float*)d_in[10];
  const float* caob = (const float*)d_in[11];
  const float* f1w  = (const float*)d_in[12];
  const float* f1b  = (const float*)d_in[13];
  const float* f2w  = (const float*)d_in[14];
  const float* f2b  = (const float*)d_in[15];
  const float* l1g  = (const float*)d_in[16];
  const float* l1b  = (const float*)d_in[17];
  const float* l2g  = (const float*)d_in[18];
  const float* l2b  = (const float*)d_in[19];
  const float* l3g  = (const float*)d_in[20];
  const float* l3b  = (const float*)d_in[21];
  const float* lng  = (const float*)d_in[22];
  const float* lnb  = (const float*)d_in[23];
  const float* Wout = (const float*)d_in[24];
  const float* bout = (const float*)d_in[25];
  float* out = (float*)d_out;

  // -------------------- workspace layout (u16 elements) --------------------
  u16* ws = (u16*)d_ws;
  size_t off = 0;
  auto alloc = [&](size_t n) { u16* p = ws + off; off += n; return p; };
  // persistent region (~82 MB)
  u16* ctx0  = alloc((size_t)32 * 64 * 512);          // 1,048,576
  u16* cabuf = alloc((size_t)NLAY * SB * 512);        // 8,388,608
  u16* memh  = alloc((size_t)SB * 512);               // 1,048,576
  u16* tmpv  = alloc((size_t)SB * 512);               // 1,048,576
  u16* wqkvT = alloc((size_t)NLAY * 1536 * 512);      // 6,291,456
  u16* woutT = alloc((size_t)NLAY * 512 * 512);       // 2,097,152
  u16* wf1T  = alloc((size_t)NLAY * 2048 * 512);      // 8,388,608
  u16* wf2T  = alloc((size_t)NLAY * 512 * 2048);      // 8,388,608
  u16* wcavT = alloc((size_t)NLAY * 512 * 512);       // 2,097,152
  u16* wcaoT = alloc((size_t)NLAY * 512 * 512);       // 2,097,152
  int* rowmap = (int*)alloc(RAGG * 2);                // row -> seq id

  // ragged chunk row budget (3072 bf16 per row across hb/regA/tmpb)
  size_t avail = ws_size / 2 > off ? ws_size / 2 - off : 0;
  size_t Ralloc = avail / 3072;
  Ralloc = Ralloc / 128 * 128;
  if (Ralloc > RAGG) Ralloc = RAGG;
  // (minimum viable: one step (2048 rows); assume ws_size >= ~100 MB)

  u16* hb   = alloc(Ralloc * 512);    // residual stream for the chunk
  u16* regA = alloc(Ralloc * 2048);   // qkv (1536)+attn (512) / ffn-mid (2048)
  u16* tmpb = alloc(Ralloc * 512);    // GEMM output scratch
  u16* qkvb = regA;                   // [rows][1536]
  u16* attb = regA + Ralloc * 1536;   // [rows][512]
  u16* midb = regA;                   // [rows][2048]

  // -------------------- weight transpose + cast (every launch) -------------
  dim3 tb(32, 8);
  k_tcast<<<dim3(48, 16, 8), tb, 0, stream>>>(saqw, wqkvT, 512, 1536, 1536, 0);
  k_tcast<<<dim3(16, 16, 8), tb, 0, stream>>>(saow, woutT, 512, 512, 512, 0);
  k_tcast<<<dim3(64, 16, 8), tb, 0, stream>>>(f1w, wf1T, 512, 2048, 2048, 0);
  k_tcast<<<dim3(16, 64, 8), tb, 0, stream>>>(f2w, wf2T, 2048, 512, 512, 0);
  k_tcast<<<dim3(16, 16, 8), tb, 0, stream>>>(caqw, wcavT, 512, 512, 1536, 1024);  // v-slice of ca qkv
  k_tcast<<<dim3(16, 16, 8), tb, 0, stream>>>(caow, wcaoT, 512, 512, 512, 0);

  k_ctx<<<4096, 256, 0, stream>>>(x, W_in, b_in, ctx0);
  k_vq<<<2048, 256, 0, stream>>>(x, cb, W_in, b_in, memh);
  k_map<<<2048, 64, 0, stream>>>(rowmap);

  // Cross-attention collapses to a per-(s,b) constant: (mem_h@Wv+bv)@Wout+bout
  for (int l = 0; l < NLAY; ++l) {
    gemm_bt<0><<<dim3(4, 16), 256, 0, stream>>>(memh, wcavT + (size_t)l * 512 * 512,
                                                caqb + (size_t)l * 1536 + 1024, tmpv, 512, 512);
    gemm_bt<0><<<dim3(4, 16), 256, 0, stream>>>(tmpv, wcaoT + (size_t)l * 512 * 512,
                                                caob + (size_t)l * 512, cabuf + (size_t)l * SB * 512, 512, 512);
  }

  // -------------------- main decoder, ragged chunks over steps --------------
  int sstart = 0;
  while (sstart < 64) {
    // greedy-pack steps while padded rows fit the budget
    int send = sstart;
    size_t rows = 0;
    while (send < 64) {
      size_t nr = rows + (size_t)32 * (send + 1);
      size_t pr = (nr + 127) / 128 * 128;
      if (pr > Ralloc && send > sstart) break;
      rows = nr; ++send;
      if (pr > Ralloc) break;  // single oversized step: shouldn't happen, bail
    }
    const size_t row0 = (size_t)16 * sstart * (sstart + 1);  // 32*prefix(sstart)
    const size_t rows_pad = (rows + 127) / 128 * 128;
    const int mg = (int)(rows_pad / 128);
    const int ns = send - sstart;

    k_rep<<<ns * 32, 256, 0, stream>>>(ctx0, hb, sstart, row0);
    for (int l = 0; l < NLAY; ++l) {
      gemm_bt<0><<<dim3(12, mg), 256, 0, stream>>>(hb, wqkvT + (size_t)l * 1536 * 512,
                                                   saqb + (size_t)l * 1536, qkvb, 1536, 512);
      k_attn<<<dim3(8, 32, ns), 256, 0, stream>>>(qkvb, attb, sstart, row0);
      gemm_bt<0><<<dim3(4, mg), 256, 0, stream>>>(attb, woutT + (size_t)l * 512 * 512,
                                                  saob + (size_t)l * 512, tmpb, 512, 512);
      k_ln<1><<<(int)(rows / 4), 256, 0, stream>>>(hb, tmpb, cabuf + (size_t)l * SB * 512,
                                                   rowmap, row0,
                                                   l1g + l * 512, l1b + l * 512, l2g + l * 512, l2b + l * 512);
      gemm_bt<1><<<dim3(16, mg), 256, 0, stream>>>(hb, wf1T + (size_t)l * 2048 * 512,
                                                   f1b + (size_t)l * 2048, midb, 2048, 512);
      gemm_bt<0><<<dim3(4, mg), 256, 0, stream>>>(midb, wf2T + (size_t)l * 512 * 2048,
                                                  f2b + (size_t)l * 512, tmpb, 512, 2048);
      k_ln<0><<<(int)(rows / 4), 256, 0, stream>>>(hb, tmpb, nullptr, rowmap, row0,
                                                   l3g + l * 512, l3b + l * 512, nullptr, nullptr);
    }
    k_final<<<ns * 32, 64, 0, stream>>>(hb, lng, lnb, Wout, bout, out, sstart, row0);
    sstart = send;
  }
}

// Round 5
// 7550.219 us; speedup vs baseline: 1.8907x; 1.0734x over previous
//
#include <hip/hip_runtime.h>
#include <hip/hip_bf16.h>
#include <math.h>

#define DEV __device__ __forceinline__

typedef unsigned short u16;
typedef __attribute__((ext_vector_type(8))) short s8v;   // 8 x bf16 (4 VGPRs)
typedef __attribute__((ext_vector_type(4))) float f4v;   // MFMA accumulator

// Problem constants
constexpr int NLAY = 8;
constexpr int SB   = 64 * 32;                 // steps * batch = 2048 sequences
constexpr size_t RAGG = 66560;                // 32 * sum_{s=0}^{63}(s+1) = 520*128

DEV float bf2f(u16 u) { unsigned x = ((unsigned)u) << 16; union { unsigned u; float f; } c; c.u = x; return c.f; }
DEV u16 f2bf(float f) { union { float f; unsigned u; } c; c.f = f; unsigned x = c.u; x += 0x7fffu + ((x >> 16) & 1u); return (u16)(x >> 16); }

DEV void load8bf(const u16* p, float* o) {
  uint4 q = *(const uint4*)p;
  o[0] = bf2f((u16)(q.x & 0xffff)); o[1] = bf2f((u16)(q.x >> 16));
  o[2] = bf2f((u16)(q.y & 0xffff)); o[3] = bf2f((u16)(q.y >> 16));
  o[4] = bf2f((u16)(q.z & 0xffff)); o[5] = bf2f((u16)(q.z >> 16));
  o[6] = bf2f((u16)(q.w & 0xffff)); o[7] = bf2f((u16)(q.w >> 16));
}
DEV void store8bf(u16* p, const float* v) {
  uint4 q;
  q.x = (unsigned)f2bf(v[0]) | ((unsigned)f2bf(v[1]) << 16);
  q.y = (unsigned)f2bf(v[2]) | ((unsigned)f2bf(v[3]) << 16);
  q.z = (unsigned)f2bf(v[4]) | ((unsigned)f2bf(v[5]) << 16);
  q.w = (unsigned)f2bf(v[6]) | ((unsigned)f2bf(v[7]) << 16);
  *(uint4*)p = q;
}

// ragged row offset of sequence (s, b): rows 0..s live at [soff, soff+s]
DEV size_t seqoff(int s, int b) { return (size_t)16 * s * (s + 1) + (size_t)b * (s + 1); }

// async global->LDS, 16B per lane, LDS dest wave-uniform base + lane*16
DEV void cp16(const void* g, void* l) {
  __builtin_amdgcn_global_load_lds((const __attribute__((address_space(1))) unsigned*)g,
                                   (__attribute__((address_space(3))) unsigned*)l, 16, 0, 0);
}

// ---------------------------------------------------------------------------
// C[M,N] = A[M,K] @ Bt[N,K]^T + bias, bf16 in / bf16 out, fp32 accum.
// 128x128 tile, BK=64, 4 waves, 16x16x32 bf16 MFMA. M,N,K divisible.
// ---------------------------------------------------------------------------
template<int RELU>
__global__ __launch_bounds__(256) void gemm_bt(const u16* __restrict__ A, const u16* __restrict__ Bt,
                                               const float* __restrict__ bias, u16* __restrict__ C,
                                               int N, int K) {
  __shared__ u16 As[128 * 64];
  __shared__ u16 Bs[128 * 64];
  const int tid = threadIdx.x, w = tid >> 6, lane = tid & 63;
  const int lrow = lane & 15, lquad = lane >> 4;
  const int m0 = blockIdx.y * 128, n0 = blockIdx.x * 128;
  const int wm = (w & 1) * 64, wn = (w >> 1) * 64;
  const int srow = lane >> 3, sch = (lane & 7) * 8;
  f4v acc[4][4] = {};
  for (int kt = 0; kt < K; kt += 64) {
    __syncthreads();
#pragma unroll
    for (int c = 0; c < 4; ++c) {
      int seg = w * 4 + c;  // 8 rows of the 128-row tile per call
      cp16(A + (size_t)(m0 + seg * 8 + srow) * K + kt + sch, &As[seg * 512]);
      cp16(Bt + (size_t)(n0 + seg * 8 + srow) * K + kt + sch, &Bs[seg * 512]);
    }
    __syncthreads();
#pragma unroll
    for (int kc = 0; kc < 2; ++kc) {
      s8v a[4], b[4];
#pragma unroll
      for (int t = 0; t < 4; ++t) {
        a[t] = *(const s8v*)&As[(wm + t * 16 + lrow) * 64 + kc * 32 + lquad * 8];
        b[t] = *(const s8v*)&Bs[(wn + t * 16 + lrow) * 64 + kc * 32 + lquad * 8];
      }
#pragma unroll
      for (int mt = 0; mt < 4; ++mt)
#pragma unroll
        for (int nt = 0; nt < 4; ++nt)
          acc[mt][nt] = __builtin_amdgcn_mfma_f32_16x16x32_bf16(a[mt], b[nt], acc[mt][nt], 0, 0, 0);
    }
  }
#pragma unroll
  for (int nt = 0; nt < 4; ++nt) {
    int col = n0 + wn + nt * 16 + lrow;
    float bv = bias[col];
#pragma unroll
    for (int mt = 0; mt < 4; ++mt) {
      size_t rbase = (size_t)(m0 + wm + mt * 16 + lquad * 4);
#pragma unroll
      for (int j = 0; j < 4; ++j) {
        float v = acc[mt][nt][j] + bv;
        if (RELU) v = fmaxf(v, 0.f);
        C[(rbase + j) * (size_t)N + col] = f2bf(v);
      }
    }
  }
}

// ---------------------------------------------------------------------------
// Batched (blockIdx.z) 512x512 GEMM for the 8 CA layers: two dispatches
// replace 16 small ones.
// ---------------------------------------------------------------------------
__global__ __launch_bounds__(256) void gemm_ca(const u16* __restrict__ A0, const u16* __restrict__ Bt0,
                                               const float* __restrict__ bias0, u16* __restrict__ C0,
                                               size_t sA, size_t sB, int sBias, size_t sC) {
  const int z = blockIdx.z;
  const u16* A = A0 + sA * z;
  const u16* Bt = Bt0 + sB * z;
  const float* bias = bias0 + (size_t)sBias * z;
  u16* C = C0 + sC * z;
  const int N = 512, K = 512;
  __shared__ u16 As[128 * 64];
  __shared__ u16 Bs[128 * 64];
  const int tid = threadIdx.x, w = tid >> 6, lane = tid & 63;
  const int lrow = lane & 15, lquad = lane >> 4;
  const int m0 = blockIdx.y * 128, n0 = blockIdx.x * 128;
  const int wm = (w & 1) * 64, wn = (w >> 1) * 64;
  const int srow = lane >> 3, sch = (lane & 7) * 8;
  f4v acc[4][4] = {};
  for (int kt = 0; kt < K; kt += 64) {
    __syncthreads();
#pragma unroll
    for (int c = 0; c < 4; ++c) {
      int seg = w * 4 + c;
      cp16(A + (size_t)(m0 + seg * 8 + srow) * K + kt + sch, &As[seg * 512]);
      cp16(Bt + (size_t)(n0 + seg * 8 + srow) * K + kt + sch, &Bs[seg * 512]);
    }
    __syncthreads();
#pragma unroll
    for (int kc = 0; kc < 2; ++kc) {
      s8v a[4], b[4];
#pragma unroll
      for (int t = 0; t < 4; ++t) {
        a[t] = *(const s8v*)&As[(wm + t * 16 + lrow) * 64 + kc * 32 + lquad * 8];
        b[t] = *(const s8v*)&Bs[(wn + t * 16 + lrow) * 64 + kc * 32 + lquad * 8];
      }
#pragma unroll
      for (int mt = 0; mt < 4; ++mt)
#pragma unroll
        for (int nt = 0; nt < 4; ++nt)
          acc[mt][nt] = __builtin_amdgcn_mfma_f32_16x16x32_bf16(a[mt], b[nt], acc[mt][nt], 0, 0, 0);
    }
  }
#pragma unroll
  for (int nt = 0; nt < 4; ++nt) {
    int col = n0 + wn + nt * 16 + lrow;
    float bv = bias[col];
#pragma unroll
    for (int mt = 0; mt < 4; ++mt) {
      size_t rbase = (size_t)(m0 + wm + mt * 16 + lquad * 4);
#pragma unroll
      for (int j = 0; j < 4; ++j)
        C[(rbase + j) * (size_t)N + col] = f2bf(acc[mt][nt][j] + bv);
    }
  }
}

// ---------------------------------------------------------------------------
// Self-attention on ragged rows (layers 0..6): block per (h, b, local step).
// ---------------------------------------------------------------------------
__global__ __launch_bounds__(256) void k_attn(const u16* __restrict__ qkv, u16* __restrict__ o,
                                              int sbase, size_t row0) {
  const int h = blockIdx.x, b = blockIdx.y, sl = blockIdx.z;
  const int s = sbase + sl;
  const size_t soff = seqoff(s, b) - row0;
  __shared__ u16 qs[64][72], ks[64][72], vts[64][72], ps[64][72];
  const int tid = threadIdx.x;
  const int row = tid >> 2, c16 = (tid & 3) * 16;
  const int rcl = row <= s ? row : s;
  {
    const u16* qp = qkv + (soff + rcl) * 1536 + h * 64 + c16;
    *(uint4*)&qs[row][c16]     = *(const uint4*)qp;
    *(uint4*)&qs[row][c16 + 8] = *(const uint4*)(qp + 8);
    *(uint4*)&ks[row][c16]     = *(const uint4*)(qp + 512);
    *(uint4*)&ks[row][c16 + 8] = *(const uint4*)(qp + 520);
    uint4 v0 = *(const uint4*)(qp + 1024), v1 = *(const uint4*)(qp + 1032);
    unsigned arr[8] = {v0.x, v0.y, v0.z, v0.w, v1.x, v1.y, v1.z, v1.w};
#pragma unroll
    for (int j = 0; j < 8; ++j) {  // transpose v into vts[d][l]
      vts[c16 + 2 * j][row]     = (u16)(arr[j] & 0xffff);
      vts[c16 + 2 * j + 1][row] = (u16)(arr[j] >> 16);
    }
  }
  __syncthreads();
  const int w = tid >> 6, lane = tid & 63, lrow = lane & 15, lquad = lane >> 4;
  f4v sc[4] = {};
  {
    s8v aq[2];
#pragma unroll
    for (int kc = 0; kc < 2; ++kc) aq[kc] = *(const s8v*)&qs[w * 16 + lrow][kc * 32 + lquad * 8];
#pragma unroll
    for (int nt = 0; nt < 4; ++nt)
#pragma unroll
      for (int kc = 0; kc < 2; ++kc) {
        s8v bk = *(const s8v*)&ks[nt * 16 + lrow][kc * 32 + lquad * 8];
        sc[nt] = __builtin_amdgcn_mfma_f32_16x16x32_bf16(aq[kc], bk, sc[nt], 0, 0, 0);
      }
  }
#pragma unroll
  for (int j = 0; j < 4; ++j) {  // per-row softmax (row = w*16 + lquad*4 + j)
    float v[4]; float mx = -3.0e38f;
#pragma unroll
    for (int nt = 0; nt < 4; ++nt) {
      int col = nt * 16 + lrow;
      float xx = sc[nt][j] * 0.125f;   // 1/sqrt(64)
      if (col > s) xx = -1e9f;         // key mask
      v[nt] = xx; mx = fmaxf(mx, xx);
    }
#pragma unroll
    for (int m = 1; m < 16; m <<= 1) mx = fmaxf(mx, __shfl_xor(mx, m));
    float sum = 0.f;
#pragma unroll
    for (int nt = 0; nt < 4; ++nt) { v[nt] = __expf(v[nt] - mx); sum += v[nt]; }
#pragma unroll
    for (int m = 1; m < 16; m <<= 1) sum += __shfl_xor(sum, m);
    float inv = 1.f / sum;
    int prow = w * 16 + lquad * 4 + j;
#pragma unroll
    for (int nt = 0; nt < 4; ++nt) ps[prow][nt * 16 + lrow] = f2bf(v[nt] * inv);
  }
  // P@V: ps rows are wave-local -> no barrier needed
  f4v oc[4] = {};
  {
    s8v ap[2];
#pragma unroll
    for (int kc = 0; kc < 2; ++kc) ap[kc] = *(const s8v*)&ps[w * 16 + lrow][kc * 32 + lquad * 8];
#pragma unroll
    for (int nt = 0; nt < 4; ++nt)
#pragma unroll
      for (int kc = 0; kc < 2; ++kc) {
        s8v bv = *(const s8v*)&vts[nt * 16 + lrow][kc * 32 + lquad * 8];
        oc[nt] = __builtin_amdgcn_mfma_f32_16x16x32_bf16(ap[kc], bv, oc[nt], 0, 0, 0);
      }
  }
#pragma unroll
  for (int nt = 0; nt < 4; ++nt) {
    int col = h * 64 + nt * 16 + lrow;
#pragma unroll
    for (int j = 0; j < 4; ++j) {
      int r = w * 16 + lquad * 4 + j;
      if (r <= s) o[(soff + r) * 512 + col] = f2bf(oc[nt][j]);
    }
  }
}

// ---------------------------------------------------------------------------
// Last-layer attention: single query row per sequence. Block per (h, seq).
// kvb row = [K(512) | V(512)], ld 1024.
// ---------------------------------------------------------------------------
__global__ __launch_bounds__(64) void k_attn_last(const u16* __restrict__ qb, const u16* __restrict__ kvb,
                                                  u16* __restrict__ attl, int sbase, size_t row0) {
  const int h = blockIdx.x;            // 0..7
  const int r = blockIdx.y;            // sl*32 + b
  const int sl = r >> 5, b = r & 31;
  const int s = sbase + sl;
  const size_t soff = seqoff(s, b) - row0;
  const int lane = threadIdx.x;
  __shared__ float qsm[64], ps[64];
  qsm[lane] = bf2f(qb[(size_t)r * 512 + h * 64 + lane]);
  __syncthreads();
  float sc = -3.0e38f;
  if (lane <= s) {
    const u16* kp = kvb + (soff + lane) * 1024 + h * 64;
    float acc = 0.f;
#pragma unroll
    for (int d = 0; d < 64; d += 8) {
      float kv[8]; load8bf(kp + d, kv);
#pragma unroll
      for (int i = 0; i < 8; ++i) acc += qsm[d + i] * kv[i];
    }
    sc = acc * 0.125f;
  }
  float mx = sc;
#pragma unroll
  for (int m = 1; m < 64; m <<= 1) mx = fmaxf(mx, __shfl_xor(mx, m));
  float e = (lane <= s) ? __expf(sc - mx) : 0.f;
  float sum = e;
#pragma unroll
  for (int m = 1; m < 64; m <<= 1) sum += __shfl_xor(sum, m);
  ps[lane] = e / sum;
  __syncthreads();
  float acc = 0.f;
  for (int k = 0; k <= s; ++k)
    acc += ps[k] * bf2f(kvb[(soff + k) * 1024 + 512 + h * 64 + lane]);
  attl[(size_t)r * 512 + h * 64 + lane] = f2bf(acc);
}

// ---------------------------------------------------------------------------
// Residual + LN (layers 0..6). One wave per 512-row. CA via row->seq map.
// ---------------------------------------------------------------------------
template<int HAS2>
__global__ __launch_bounds__(256) void k_ln(u16* __restrict__ hb, const u16* __restrict__ tmpb,
                                            const u16* __restrict__ cab, const int* __restrict__ map,
                                            size_t row0,
                                            const float* __restrict__ g1, const float* __restrict__ b1,
                                            const float* __restrict__ g2, const float* __restrict__ b2) {
  const int row = blockIdx.x * 4 + (threadIdx.x >> 6);
  const int lane = threadIdx.x & 63;
  const size_t off = (size_t)row * 512 + lane * 8;
  float hv[8], tv[8], t[8];
  load8bf(hb + off, hv); load8bf(tmpb + off, tv);
  float s = 0.f, ss = 0.f;
#pragma unroll
  for (int i = 0; i < 8; ++i) { t[i] = hv[i] + tv[i]; s += t[i]; ss += t[i] * t[i]; }
#pragma unroll
  for (int m = 1; m < 64; m <<= 1) { s += __shfl_xor(s, m); ss += __shfl_xor(ss, m); }
  float mean = s * (1.f / 512.f);
  float inv = 1.f / sqrtf(ss * (1.f / 512.f) - mean * mean + 1e-5f);
  float gv[8], bv[8];
  *(float4*)&gv[0] = *(const float4*)(g1 + lane * 8); *(float4*)&gv[4] = *(const float4*)(g1 + lane * 8 + 4);
  *(float4*)&bv[0] = *(const float4*)(b1 + lane * 8); *(float4*)&bv[4] = *(const float4*)(b1 + lane * 8 + 4);
  if (HAS2) {
    const int seq = map[row0 + row];
    float cv[8]; load8bf(cab + (size_t)seq * 512 + lane * 8, cv);
    float s2 = 0.f, ss2 = 0.f;
#pragma unroll
    for (int i = 0; i < 8; ++i) { float n = (t[i] - mean) * inv * gv[i] + bv[i] + cv[i]; t[i] = n; s2 += n; ss2 += n * n; }
#pragma unroll
    for (int m = 1; m < 64; m <<= 1) { s2 += __shfl_xor(s2, m); ss2 += __shfl_xor(ss2, m); }
    float mean2 = s2 * (1.f / 512.f);
    float inv2 = 1.f / sqrtf(ss2 * (1.f / 512.f) - mean2 * mean2 + 1e-5f);
    float g2v[8], b2v[8];
    *(float4*)&g2v[0] = *(const float4*)(g2 + lane * 8); *(float4*)&g2v[4] = *(const float4*)(g2 + lane * 8 + 4);
    *(float4*)&b2v[0] = *(const float4*)(b2 + lane * 8); *(float4*)&b2v[4] = *(const float4*)(b2 + lane * 8 + 4);
#pragma unroll
    for (int i = 0; i < 8; ++i) t[i] = (t[i] - mean2) * inv2 * g2v[i] + b2v[i];
  } else {
#pragma unroll
    for (int i = 0; i < 8; ++i) t[i] = (t[i] - mean) * inv * gv[i] + bv[i];
  }
  store8bf(hb + off, t);
}

// ---------------------------------------------------------------------------
// Residual + LN for the gathered last rows (layer 7). seq computed directly.
// ---------------------------------------------------------------------------
template<int HAS2>
__global__ __launch_bounds__(256) void k_ln_last(u16* __restrict__ gl, const u16* __restrict__ tmpl,
                                                 const u16* __restrict__ cab, int sbase,
                                                 const float* __restrict__ g1, const float* __restrict__ b1,
                                                 const float* __restrict__ g2, const float* __restrict__ b2) {
  const int row = blockIdx.x * 4 + (threadIdx.x >> 6);
  const int lane = threadIdx.x & 63;
  const size_t off = (size_t)row * 512 + lane * 8;
  float hv[8], tv[8], t[8];
  load8bf(gl + off, hv); load8bf(tmpl + off, tv);
  float s = 0.f, ss = 0.f;
#pragma unroll
  for (int i = 0; i < 8; ++i) { t[i] = hv[i] + tv[i]; s += t[i]; ss += t[i] * t[i]; }
#pragma unroll
  for (int m = 1; m < 64; m <<= 1) { s += __shfl_xor(s, m); ss += __shfl_xor(ss, m); }
  float mean = s * (1.f / 512.f);
  float inv = 1.f / sqrtf(ss * (1.f / 512.f) - mean * mean + 1e-5f);
  float gv[8], bv[8];
  *(float4*)&gv[0] = *(const float4*)(g1 + lane * 8); *(float4*)&gv[4] = *(const float4*)(g1 + lane * 8 + 4);
  *(float4*)&bv[0] = *(const float4*)(b1 + lane * 8); *(float4*)&bv[4] = *(const float4*)(b1 + lane * 8 + 4);
  if (HAS2) {
    const int seq = (sbase + (row >> 5)) * 32 + (row & 31);
    float cv[8]; load8bf(cab + (size_t)seq * 512 + lane * 8, cv);
    float s2 = 0.f, ss2 = 0.f;
#pragma unroll
    for (int i = 0; i < 8; ++i) { float n = (t[i] - mean) * inv * gv[i] + bv[i] + cv[i]; t[i] = n; s2 += n; ss2 += n * n; }
#pragma unroll
    for (int m = 1; m < 64; m <<= 1) { s2 += __shfl_xor(s2, m); ss2 += __shfl_xor(ss2, m); }
    float mean2 = s2 * (1.f / 512.f);
    float inv2 = 1.f / sqrtf(ss2 * (1.f / 512.f) - mean2 * mean2 + 1e-5f);
    float g2v[8], b2v[8];
    *(float4*)&g2v[0] = *(const float4*)(g2 + lane * 8); *(float4*)&g2v[4] = *(const float4*)(g2 + lane * 8 + 4);
    *(float4*)&b2v[0] = *(const float4*)(b2 + lane * 8); *(float4*)&b2v[4] = *(const float4*)(b2 + lane * 8 + 4);
#pragma unroll
    for (int i = 0; i < 8; ++i) t[i] = (t[i] - mean2) * inv2 * g2v[i] + b2v[i];
  } else {
#pragma unroll
    for (int i = 0; i < 8; ++i) t[i] = (t[i] - mean) * inv * gv[i] + bv[i];
  }
  store8bf(gl + off, t);
}

// ---------------------------------------------------------------------------
// ctx0[b,l,:] = x_full[b,l] @ W_in + b_in + PE[l]
// ---------------------------------------------------------------------------
__global__ __launch_bounds__(256) void k_ctx(const float* __restrict__ x, const float* __restrict__ W_in,
                                             const float* __restrict__ b_in, u16* __restrict__ ctx0) {
  const int e = blockIdx.x * 256 + threadIdx.x;   // over B*L*D = 1M
  const int d = e & 511, l = (e >> 9) & 63, b = e >> 15;
  float acc = b_in[d];
  if (l > 0) {
    const float* xr = x + (size_t)(b * 64 + l - 1) * 32;
#pragma unroll 8
    for (int z = 0; z < 32; ++z) acc += xr[z] * W_in[z * 512 + d];
  }
  const float dv = __expf(-9.210340371976184f * (float)(d & ~1) * (1.f / 512.f));
  const float ang = (float)l * dv;
  acc += (d & 1) ? cosf(ang) : sinf(ang);
  ctx0[(size_t)e] = f2bf(acc);
}

// ---------------------------------------------------------------------------
__global__ __launch_bounds__(64) void k_map(int* __restrict__ map) {
  const int seq = blockIdx.x;           // s*32 + b
  const int s = seq >> 5, b = seq & 31;
  const int l = threadIdx.x;
  if (l <= s) map[seqoff(s, b) + l] = seq;
}

// ---------------------------------------------------------------------------
__global__ __launch_bounds__(256) void k_rep(const u16* __restrict__ ctx0, u16* __restrict__ hb,
                                             int sbase, size_t row0) {
  const int sl = blockIdx.x >> 5, b = blockIdx.x & 31;
  const int s = sbase + sl;
  const size_t dst0 = seqoff(s, b) - row0;
  const int tid = threadIdx.x;
  for (int idx = tid; idx < (s + 1) * 64; idx += 256) {
    const int l = idx >> 6, d8 = idx & 63;
    *(uint4*)(hb + (dst0 + l) * 512 + d8 * 8) =
        *(const uint4*)(ctx0 + ((size_t)(b * 64 + l) * 512) + d8 * 8);
  }
}

// ---------------------------------------------------------------------------
// Gather last valid row of each sequence into a compact buffer.
// ---------------------------------------------------------------------------
__global__ __launch_bounds__(64) void k_gather(const u16* __restrict__ hb, u16* __restrict__ gl,
                                               int sbase, size_t row0) {
  const int r = blockIdx.x; const int sl = r >> 5, b = r & 31; const int s = sbase + sl;
  const size_t src = (seqoff(s, b) - row0 + s) * 512;
  const int lane = threadIdx.x;
  *(uint4*)(gl + (size_t)r * 512 + lane * 8) = *(const uint4*)(hb + src + lane * 8);
}

// ---------------------------------------------------------------------------
// VQ nearest-neighbor + mem_h = codebook[kmin] @ W_in + b_in.
// ILP: 4 independent accumulator chains, xs in registers.
// ---------------------------------------------------------------------------
__global__ __launch_bounds__(256) void k_vq(const float* __restrict__ x, const float* __restrict__ cb,
                                            const float* __restrict__ W_in, const float* __restrict__ b_in,
                                            u16* __restrict__ memh) {
  const int tok = blockIdx.x;              // = s*32 + b
  const int s = tok >> 5, b = tok & 31;
  const int tid = threadIdx.x;
  __shared__ float xs[32], cs[32];
  __shared__ float rd[256]; __shared__ int ri[256];
  if (tid < 32) xs[tid] = x[(size_t)(b * 64 + s) * 32 + tid];  // mem token = x[b, s]
  __syncthreads();
  float xr[32];
#pragma unroll
  for (int i = 0; i < 32; ++i) xr[i] = xs[i];
  float bd = 3.0e38f; int bi = 0;
#pragma unroll 2
  for (int c = tid; c < 8192; c += 256) {
    const float4* cr = (const float4*)(cb + (size_t)c * 32);
    float d0 = 0.f, d1 = 0.f, d2 = 0.f, d3 = 0.f;
#pragma unroll
    for (int z4 = 0; z4 < 8; ++z4) {
      float4 cv = cr[z4];
      float t0 = xr[z4 * 4 + 0] - cv.x, t1 = xr[z4 * 4 + 1] - cv.y;
      float t2 = xr[z4 * 4 + 2] - cv.z, t3 = xr[z4 * 4 + 3] - cv.w;
      d0 += t0 * t0; d1 += t1 * t1; d2 += t2 * t2; d3 += t3 * t3;
    }
    float d = (d0 + d1) + (d2 + d3);
    if (d < bd) { bd = d; bi = c; }
  }
  rd[tid] = bd; ri[tid] = bi;
  __syncthreads();
  for (int st = 128; st > 0; st >>= 1) {
    if (tid < st) {
      float dn = rd[tid + st]; int in2 = ri[tid + st];
      if (dn < rd[tid] || (dn == rd[tid] && in2 < ri[tid])) { rd[tid] = dn; ri[tid] = in2; }
    }
    __syncthreads();
  }
  const int kmin = ri[0];
  if (tid < 32) cs[tid] = cb[(size_t)kmin * 32 + tid];
  __syncthreads();
  for (int o = tid; o < 512; o += 256) {
    float a = b_in[o];
#pragma unroll 8
    for (int z = 0; z < 32; ++z) a += cs[z] * W_in[z * 512 + o];
    memh[(size_t)tok * 512 + o] = f2bf(a);
  }
}

// ---------------------------------------------------------------------------
// Final: out[b,s,:] = LN(gl[r,:]) @ W_out + b_out. Block per seq r = sl*32+b.
// ---------------------------------------------------------------------------
__global__ __launch_bounds__(64) void k_final(const u16* __restrict__ gl, const float* __restrict__ g,
                                              const float* __restrict__ bta, const float* __restrict__ Wout,
                                              const float* __restrict__ bout, float* __restrict__ out,
                                              int sbase) {
  const int blk = blockIdx.x;            // sl*32 + b
  const int s = sbase + (blk >> 5), b = blk & 31;
  const int lane = threadIdx.x;
  __shared__ float ns[512];
  const size_t roff = (size_t)blk * 512;
  float v[8]; load8bf(gl + roff + lane * 8, v);
  float sm = 0.f, ssm = 0.f;
#pragma unroll
  for (int i = 0; i < 8; ++i) { sm += v[i]; ssm += v[i] * v[i]; }
#pragma unroll
  for (int m = 1; m < 64; m <<= 1) { sm += __shfl_xor(sm, m); ssm += __shfl_xor(ssm, m); }
  float mean = sm * (1.f / 512.f);
  float inv = 1.f / sqrtf(ssm * (1.f / 512.f) - mean * mean + 1e-5f);
#pragma unroll
  for (int i = 0; i < 8; ++i) ns[lane * 8 + i] = (v[i] - mean) * inv * g[lane * 8 + i] + bta[lane * 8 + i];
  __syncthreads();
  const int col = lane & 31, half = lane >> 5;
  float a = 0.f;
  for (int k = half * 256; k < half * 256 + 256; ++k) a += ns[k] * Wout[(size_t)k * 32 + col];
  a += __shfl_xor(a, 32);
  if (lane < 32) out[((size_t)b * 64 + s) * 32 + col] = a + bout[col];
}

// ---------------------------------------------------------------------------
// Transpose + fp32->bf16 cast of weights: dst[l][c][r] = src[l][r][col0 + c]
// ---------------------------------------------------------------------------
__global__ void k_tcast(const float* __restrict__ src, u16* __restrict__ dst, int R, int C, int ld, int col0) {
  const int l = blockIdx.z;
  src += (size_t)l * R * ld;
  dst += (size_t)l * R * C;
  __shared__ float t[32][33];
  const int c0 = blockIdx.x * 32, r0 = blockIdx.y * 32;
  const int tx = threadIdx.x, ty = threadIdx.y;
#pragma unroll
  for (int k = 0; k < 4; ++k)
    t[ty + 8 * k][tx] = src[(size_t)(r0 + ty + 8 * k) * ld + col0 + c0 + tx];
  __syncthreads();
#pragma unroll
  for (int k = 0; k < 4; ++k)
    dst[(size_t)(c0 + ty + 8 * k) * R + r0 + tx] = f2bf(t[tx][ty + 8 * k]);
}

// ---------------------------------------------------------------------------
extern "C" void kernel_launch(void* const* d_in, const int* in_sizes, int n_in,
                              void* d_out, int out_size, void* d_ws, size_t ws_size,
                              hipStream_t stream) {
  (void)in_sizes; (void)n_in; (void)out_size;
  const float* x    = (const float*)d_in[0];
  const float* cb   = (const float*)d_in[1];
  const float* W_in = (const float*)d_in[2];
  const float* b_in = (const float*)d_in[3];
  const float* saqw = (const float*)d_in[4];
  const float* saqb = (const float*)d_in[5];
  const float* saow = (const float*)d_in[6];
  const float* saob = (const float*)d_in[7];
  const float* caqw = (const float*)d_in[8];
  const float* caqb = (const float*)d_in[9];
  const float* caow = (const float*)d_in[10];
  const float* caob = (const float*)d_in[11];
  const float* f1w  = (const float*)d_in[12];
  const float* f1b  = (const float*)d_in[13];
  const float* f2w  = (const float*)d_in[14];
  const float* f2b  = (const float*)d_in[15];
  const float* l1g  = (const float*)d_in[16];
  const float* l1b  = (const float*)d_in[17];
  const float* l2g  = (const float*)d_in[18];
  const float* l2b  = (const float*)d_in[19];
  const float* l3g  = (const float*)d_in[20];
  const float* l3b  = (const float*)d_in[21];
  const float* lng  = (const float*)d_in[22];
  const float* lnb  = (const float*)d_in[23];
  const float* Wout = (const float*)d_in[24];
  const float* bout = (const float*)d_in[25];
  float* out = (float*)d_out;

  // -------------------- workspace layout (u16 elements) --------------------
  u16* ws = (u16*)d_ws;
  size_t off = 0;
  auto alloc = [&](size_t n) { u16* p = ws + off; off += n; return p; };
  // persistent region (~97 MB)
  u16* ctx0  = alloc((size_t)32 * 64 * 512);          // 1,048,576
  u16* cabuf = alloc((size_t)NLAY * SB * 512);        // 8,388,608
  u16* memh  = alloc((size_t)SB * 512);               // 1,048,576
  u16* tmpv8 = alloc((size_t)NLAY * SB * 512);        // 8,388,608 (CA mid; reused as last-layer bufs)
  u16* wqkvT = alloc((size_t)NLAY * 1536 * 512);      // 6,291,456
  u16* woutT = alloc((size_t)NLAY * 512 * 512);       // 2,097,152
  u16* wf1T  = alloc((size_t)NLAY * 2048 * 512);      // 8,388,608
  u16* wf2T  = alloc((size_t)NLAY * 512 * 2048);      // 8,388,608
  u16* wcavT = alloc((size_t)NLAY * 512 * 512);       // 2,097,152
  u16* wcaoT = alloc((size_t)NLAY * 512 * 512);       // 2,097,152
  int* rowmap = (int*)alloc(RAGG * 2);                // row -> seq id

  // last-layer buffers alias tmpv8 (dead after CA precompute): need 8M el
  u16* glast = tmpv8;                    // [2048][512]
  u16* qb    = tmpv8 + 1048576;          // [2048][512]
  u16* attl  = tmpv8 + 2 * 1048576;      // [2048][512]
  u16* tmpl  = tmpv8 + 3 * 1048576;      // [2048][512]
  u16* midl  = tmpv8 + 4 * 1048576;      // [2048][2048]

  // ragged chunk row budget (3072 bf16 per row across hb/regA/tmpb)
  size_t avail = ws_size / 2 > off ? ws_size / 2 - off : 0;
  size_t Ralloc = avail / 3072;
  Ralloc = Ralloc / 128 * 128;
  if (Ralloc > RAGG) Ralloc = RAGG;

  u16* hb   = alloc(Ralloc * 512);    // residual stream for the chunk
  u16* regA = alloc(Ralloc * 2048);   // qkv (1536)+attn (512) / ffn-mid (2048) / kv (1024)
  u16* tmpb = alloc(Ralloc * 512);    // GEMM output scratch
  u16* qkvb = regA;                   // [rows][1536]
  u16* attb = regA + Ralloc * 1536;   // [rows][512]
  u16* midb = regA;                   // [rows][2048]
  u16* kvb  = regA;                   // [rows][1024] (layer 7)

  // -------------------- weight transpose + cast (every launch) -------------
  dim3 tb(32, 8);
  k_tcast<<<dim3(48, 16, 8), tb, 0, stream>>>(saqw, wqkvT, 512, 1536, 1536, 0);
  k_tcast<<<dim3(16, 16, 8), tb, 0, stream>>>(saow, woutT, 512, 512, 512, 0);
  k_tcast<<<dim3(64, 16, 8), tb, 0, stream>>>(f1w, wf1T, 512, 2048, 2048, 0);
  k_tcast<<<dim3(16, 64, 8), tb, 0, stream>>>(f2w, wf2T, 2048, 512, 512, 0);
  k_tcast<<<dim3(16, 16, 8), tb, 0, stream>>>(caqw, wcavT, 512, 512, 1536, 1024);  // v-slice of ca qkv
  k_tcast<<<dim3(16, 16, 8), tb, 0, stream>>>(caow, wcaoT, 512, 512, 512, 0);

  k_ctx<<<4096, 256, 0, stream>>>(x, W_in, b_in, ctx0);
  k_vq<<<2048, 256, 0, stream>>>(x, cb, W_in, b_in, memh);
  k_map<<<2048, 64, 0, stream>>>(rowmap);

  // Cross-attention collapses to per-(s,b) constants; batched over layers.
  gemm_ca<<<dim3(4, 16, 8), 256, 0, stream>>>(memh, wcavT, caqb + 1024, tmpv8,
                                              0, (size_t)512 * 512, 1536, (size_t)SB * 512);
  gemm_ca<<<dim3(4, 16, 8), 256, 0, stream>>>(tmpv8, wcaoT, caob, cabuf,
                                              (size_t)SB * 512, (size_t)512 * 512, 512, (size_t)SB * 512);

  // -------------------- main decoder, ragged chunks over steps --------------
  int sstart = 0;
  while (sstart < 64) {
    int send = sstart;
    size_t rows = 0;
    while (send < 64) {
      size_t nr = rows + (size_t)32 * (send + 1);
      size_t pr = (nr + 127) / 128 * 128;
      if (pr > Ralloc && send > sstart) break;
      rows = nr; ++send;
      if (pr > Ralloc) break;
    }
    const size_t row0 = (size_t)16 * sstart * (sstart + 1);
    const size_t rows_pad = (rows + 127) / 128 * 128;
    const int mg = (int)(rows_pad / 128);
    const int ns = send - sstart;
    const int nseq = ns * 32;
    const int nseqp = (nseq + 127) / 128 * 128;

    k_rep<<<nseq, 256, 0, stream>>>(ctx0, hb, sstart, row0);
    for (int l = 0; l < NLAY - 1; ++l) {
      gemm_bt<0><<<dim3(12, mg), 256, 0, stream>>>(hb, wqkvT + (size_t)l * 1536 * 512,
                                                   saqb + (size_t)l * 1536, qkvb, 1536, 512);
      k_attn<<<dim3(8, 32, ns), 256, 0, stream>>>(qkvb, attb, sstart, row0);
      gemm_bt<0><<<dim3(4, mg), 256, 0, stream>>>(attb, woutT + (size_t)l * 512 * 512,
                                                  saob + (size_t)l * 512, tmpb, 512, 512);
      k_ln<1><<<(int)(rows / 4), 256, 0, stream>>>(hb, tmpb, cabuf + (size_t)l * SB * 512,
                                                   rowmap, row0,
                                                   l1g + l * 512, l1b + l * 512, l2g + l * 512, l2b + l * 512);
      gemm_bt<1><<<dim3(16, mg), 256, 0, stream>>>(hb, wf1T + (size_t)l * 2048 * 512,
                                                   f1b + (size_t)l * 2048, midb, 2048, 512);
      gemm_bt<0><<<dim3(4, mg), 256, 0, stream>>>(midb, wf2T + (size_t)l * 512 * 2048,
                                                  f2b + (size_t)l * 512, tmpb, 512, 2048);
      k_ln<0><<<(int)(rows / 4), 256, 0, stream>>>(hb, tmpb, nullptr, rowmap, row0,
                                                   l3g + l * 512, l3b + l * 512, nullptr, nullptr);
    }
    // ---- layer 7: only row l=s of each sequence reaches the output ----
    {
      const size_t l7q = (size_t)7 * 1536 * 512;
      k_gather<<<nseq, 64, 0, stream>>>(hb, glast, sstart, row0);
      gemm_bt<0><<<dim3(8, mg), 256, 0, stream>>>(hb, wqkvT + l7q + (size_t)512 * 512,
                                                  saqb + 7 * 1536 + 512, kvb, 1024, 512);
      gemm_bt<0><<<dim3(4, nseqp / 128), 256, 0, stream>>>(glast, wqkvT + l7q,
                                                           saqb + 7 * 1536, qb, 512, 512);
      k_attn_last<<<dim3(8, nseq), 64, 0, stream>>>(qb, kvb, attl, sstart, row0);
      gemm_bt<0><<<dim3(4, nseqp / 128), 256, 0, stream>>>(attl, woutT + (size_t)7 * 512 * 512,
                                                           saob + 7 * 512, tmpl, 512, 512);
      k_ln_last<1><<<nseq / 4, 256, 0, stream>>>(glast, tmpl, cabuf + (size_t)7 * SB * 512, sstart,
                                                 l1g + 7 * 512, l1b + 7 * 512, l2g + 7 * 512, l2b + 7 * 512);
      gemm_bt<1><<<dim3(16, nseqp / 128), 256, 0, stream>>>(glast, wf1T + (size_t)7 * 2048 * 512,
                                                            f1b + (size_t)7 * 2048, midl, 2048, 512);
      gemm_bt<0><<<dim3(4, nseqp / 128), 256, 0, stream>>>(midl, wf2T + (size_t)7 * 512 * 2048,
                                                           f2b + 7 * 512, tmpl, 512, 2048);
      k_ln_last<0><<<nseq / 4, 256, 0, stream>>>(glast, tmpl, nullptr, sstart,
                                                 l3g + 7 * 512, l3b + 7 * 512, nullptr, nullptr);
      k_final<<<nseq, 64, 0, stream>>>(glast, lng, lnb, Wout, bout, out, sstart);
    }
    sstart = send;
  }
}

// Round 6
// 7413.792 us; speedup vs baseline: 1.9255x; 1.0184x over previous
//
#include <hip/hip_runtime.h>
#include <hip/hip_bf16.h>
#include <math.h>
#include <string.h>

#define DEV __device__ __forceinline__

typedef unsigned short u16;
typedef __attribute__((ext_vector_type(8))) short s8v;   // 8 x bf16 (4 VGPRs)
typedef __attribute__((ext_vector_type(4))) float f4v;   // MFMA accumulator

// Problem constants
constexpr int NLAY = 8;
constexpr int SB   = 64 * 32;                 // steps * batch = 2048 sequences
constexpr size_t RAGG = 66560;                // 32 * sum_{s=0}^{63}(s+1) = 520*128

DEV float bf2f(u16 u) { unsigned x = ((unsigned)u) << 16; union { unsigned u; float f; } c; c.u = x; return c.f; }
DEV u16 f2bf(float f) { union { float f; unsigned u; } c; c.f = f; unsigned x = c.u; x += 0x7fffu + ((x >> 16) & 1u); return (u16)(x >> 16); }

DEV void load8bf(const u16* p, float* o) {
  uint4 q = *(const uint4*)p;
  o[0] = bf2f((u16)(q.x & 0xffff)); o[1] = bf2f((u16)(q.x >> 16));
  o[2] = bf2f((u16)(q.y & 0xffff)); o[3] = bf2f((u16)(q.y >> 16));
  o[4] = bf2f((u16)(q.z & 0xffff)); o[5] = bf2f((u16)(q.z >> 16));
  o[6] = bf2f((u16)(q.w & 0xffff)); o[7] = bf2f((u16)(q.w >> 16));
}
DEV void store8bf(u16* p, const float* v) {
  uint4 q;
  q.x = (unsigned)f2bf(v[0]) | ((unsigned)f2bf(v[1]) << 16);
  q.y = (unsigned)f2bf(v[2]) | ((unsigned)f2bf(v[3]) << 16);
  q.z = (unsigned)f2bf(v[4]) | ((unsigned)f2bf(v[5]) << 16);
  q.w = (unsigned)f2bf(v[6]) | ((unsigned)f2bf(v[7]) << 16);
  *(uint4*)p = q;
}

// ragged row offset of sequence (s, b): rows 0..s live at [soff, soff+s]
DEV size_t seqoff(int s, int b) { return (size_t)16 * s * (s + 1) + (size_t)b * (s + 1); }

// async global->LDS, 16B per lane, LDS dest wave-uniform base + lane*16
DEV void cp16(const void* g, void* l) {
  __builtin_amdgcn_global_load_lds((const __attribute__((address_space(1))) unsigned*)g,
                                   (__attribute__((address_space(3))) unsigned*)l, 16, 0, 0);
}

// ---------------------------------------------------------------------------
// C[M,N] = A[M,K] @ Bt[N,K]^T + bias, bf16 in / bf16 out, fp32 accum.
// 128x128 tile, BK=64, 4 waves, 16x16x32 bf16 MFMA. M,N,K divisible.
// ---------------------------------------------------------------------------
template<int RELU>
__global__ __launch_bounds__(256) void gemm_bt(const u16* __restrict__ A, const u16* __restrict__ Bt,
                                               const float* __restrict__ bias, u16* __restrict__ C,
                                               int N, int K) {
  __shared__ u16 As[128 * 64];
  __shared__ u16 Bs[128 * 64];
  const int tid = threadIdx.x, w = tid >> 6, lane = tid & 63;
  const int lrow = lane & 15, lquad = lane >> 4;
  const int m0 = blockIdx.y * 128, n0 = blockIdx.x * 128;
  const int wm = (w & 1) * 64, wn = (w >> 1) * 64;
  const int srow = lane >> 3, sch = (lane & 7) * 8;
  f4v acc[4][4] = {};
  for (int kt = 0; kt < K; kt += 64) {
    __syncthreads();
#pragma unroll
    for (int c = 0; c < 4; ++c) {
      int seg = w * 4 + c;  // 8 rows of the 128-row tile per call
      cp16(A + (size_t)(m0 + seg * 8 + srow) * K + kt + sch, &As[seg * 512]);
      cp16(Bt + (size_t)(n0 + seg * 8 + srow) * K + kt + sch, &Bs[seg * 512]);
    }
    __syncthreads();
#pragma unroll
    for (int kc = 0; kc < 2; ++kc) {
      s8v a[4], b[4];
#pragma unroll
      for (int t = 0; t < 4; ++t) {
        a[t] = *(const s8v*)&As[(wm + t * 16 + lrow) * 64 + kc * 32 + lquad * 8];
        b[t] = *(const s8v*)&Bs[(wn + t * 16 + lrow) * 64 + kc * 32 + lquad * 8];
      }
#pragma unroll
      for (int mt = 0; mt < 4; ++mt)
#pragma unroll
        for (int nt = 0; nt < 4; ++nt)
          acc[mt][nt] = __builtin_amdgcn_mfma_f32_16x16x32_bf16(a[mt], b[nt], acc[mt][nt], 0, 0, 0);
    }
  }
#pragma unroll
  for (int nt = 0; nt < 4; ++nt) {
    int col = n0 + wn + nt * 16 + lrow;
    float bv = bias[col];
#pragma unroll
    for (int mt = 0; mt < 4; ++mt) {
      size_t rbase = (size_t)(m0 + wm + mt * 16 + lquad * 4);
#pragma unroll
      for (int j = 0; j < 4; ++j) {
        float v = acc[mt][nt][j] + bv;
        if (RELU) v = fmaxf(v, 0.f);
        C[(rbase + j) * (size_t)N + col] = f2bf(v);
      }
    }
  }
}

// ---------------------------------------------------------------------------
// Batched (blockIdx.z) 512x512 GEMM for the 8 CA layers: two dispatches
// replace 16 small ones.
// ---------------------------------------------------------------------------
__global__ __launch_bounds__(256) void gemm_ca(const u16* __restrict__ A0, const u16* __restrict__ Bt0,
                                               const float* __restrict__ bias0, u16* __restrict__ C0,
                                               size_t sA, size_t sB, int sBias, size_t sC) {
  const int z = blockIdx.z;
  const u16* A = A0 + sA * z;
  const u16* Bt = Bt0 + sB * z;
  const float* bias = bias0 + (size_t)sBias * z;
  u16* C = C0 + sC * z;
  const int N = 512, K = 512;
  __shared__ u16 As[128 * 64];
  __shared__ u16 Bs[128 * 64];
  const int tid = threadIdx.x, w = tid >> 6, lane = tid & 63;
  const int lrow = lane & 15, lquad = lane >> 4;
  const int m0 = blockIdx.y * 128, n0 = blockIdx.x * 128;
  const int wm = (w & 1) * 64, wn = (w >> 1) * 64;
  const int srow = lane >> 3, sch = (lane & 7) * 8;
  f4v acc[4][4] = {};
  for (int kt = 0; kt < K; kt += 64) {
    __syncthreads();
#pragma unroll
    for (int c = 0; c < 4; ++c) {
      int seg = w * 4 + c;
      cp16(A + (size_t)(m0 + seg * 8 + srow) * K + kt + sch, &As[seg * 512]);
      cp16(Bt + (size_t)(n0 + seg * 8 + srow) * K + kt + sch, &Bs[seg * 512]);
    }
    __syncthreads();
#pragma unroll
    for (int kc = 0; kc < 2; ++kc) {
      s8v a[4], b[4];
#pragma unroll
      for (int t = 0; t < 4; ++t) {
        a[t] = *(const s8v*)&As[(wm + t * 16 + lrow) * 64 + kc * 32 + lquad * 8];
        b[t] = *(const s8v*)&Bs[(wn + t * 16 + lrow) * 64 + kc * 32 + lquad * 8];
      }
#pragma unroll
      for (int mt = 0; mt < 4; ++mt)
#pragma unroll
        for (int nt = 0; nt < 4; ++nt)
          acc[mt][nt] = __builtin_amdgcn_mfma_f32_16x16x32_bf16(a[mt], b[nt], acc[mt][nt], 0, 0, 0);
    }
  }
#pragma unroll
  for (int nt = 0; nt < 4; ++nt) {
    int col = n0 + wn + nt * 16 + lrow;
    float bv = bias[col];
#pragma unroll
    for (int mt = 0; mt < 4; ++mt) {
      size_t rbase = (size_t)(m0 + wm + mt * 16 + lquad * 4);
#pragma unroll
      for (int j = 0; j < 4; ++j)
        C[(rbase + j) * (size_t)N + col] = f2bf(acc[mt][nt][j] + bv);
    }
  }
}

// ---------------------------------------------------------------------------
// Self-attention on ragged rows (layers 0..6): block per (h, b, local step).
// ---------------------------------------------------------------------------
__global__ __launch_bounds__(256) void k_attn(const u16* __restrict__ qkv, u16* __restrict__ o,
                                              int sbase, size_t row0) {
  const int h = blockIdx.x, b = blockIdx.y, sl = blockIdx.z;
  const int s = sbase + sl;
  const size_t soff = seqoff(s, b) - row0;
  __shared__ u16 qs[64][72], ks[64][72], vts[64][72], ps[64][72];
  const int tid = threadIdx.x;
  const int row = tid >> 2, c16 = (tid & 3) * 16;
  const int rcl = row <= s ? row : s;
  {
    const u16* qp = qkv + (soff + rcl) * 1536 + h * 64 + c16;
    *(uint4*)&qs[row][c16]     = *(const uint4*)qp;
    *(uint4*)&qs[row][c16 + 8] = *(const uint4*)(qp + 8);
    *(uint4*)&ks[row][c16]     = *(const uint4*)(qp + 512);
    *(uint4*)&ks[row][c16 + 8] = *(const uint4*)(qp + 520);
    uint4 v0 = *(const uint4*)(qp + 1024), v1 = *(const uint4*)(qp + 1032);
    unsigned arr[8] = {v0.x, v0.y, v0.z, v0.w, v1.x, v1.y, v1.z, v1.w};
#pragma unroll
    for (int j = 0; j < 8; ++j) {  // transpose v into vts[d][l]
      vts[c16 + 2 * j][row]     = (u16)(arr[j] & 0xffff);
      vts[c16 + 2 * j + 1][row] = (u16)(arr[j] >> 16);
    }
  }
  __syncthreads();
  const int w = tid >> 6, lane = tid & 63, lrow = lane & 15, lquad = lane >> 4;
  f4v sc[4] = {};
  {
    s8v aq[2];
#pragma unroll
    for (int kc = 0; kc < 2; ++kc) aq[kc] = *(const s8v*)&qs[w * 16 + lrow][kc * 32 + lquad * 8];
#pragma unroll
    for (int nt = 0; nt < 4; ++nt)
#pragma unroll
      for (int kc = 0; kc < 2; ++kc) {
        s8v bk = *(const s8v*)&ks[nt * 16 + lrow][kc * 32 + lquad * 8];
        sc[nt] = __builtin_amdgcn_mfma_f32_16x16x32_bf16(aq[kc], bk, sc[nt], 0, 0, 0);
      }
  }
#pragma unroll
  for (int j = 0; j < 4; ++j) {  // per-row softmax (row = w*16 + lquad*4 + j)
    float v[4]; float mx = -3.0e38f;
#pragma unroll
    for (int nt = 0; nt < 4; ++nt) {
      int col = nt * 16 + lrow;
      float xx = sc[nt][j] * 0.125f;   // 1/sqrt(64)
      if (col > s) xx = -1e9f;         // key mask
      v[nt] = xx; mx = fmaxf(mx, xx);
    }
#pragma unroll
    for (int m = 1; m < 16; m <<= 1) mx = fmaxf(mx, __shfl_xor(mx, m));
    float sum = 0.f;
#pragma unroll
    for (int nt = 0; nt < 4; ++nt) { v[nt] = __expf(v[nt] - mx); sum += v[nt]; }
#pragma unroll
    for (int m = 1; m < 16; m <<= 1) sum += __shfl_xor(sum, m);
    float inv = 1.f / sum;
    int prow = w * 16 + lquad * 4 + j;
#pragma unroll
    for (int nt = 0; nt < 4; ++nt) ps[prow][nt * 16 + lrow] = f2bf(v[nt] * inv);
  }
  // P@V: ps rows are wave-local -> no barrier needed
  f4v oc[4] = {};
  {
    s8v ap[2];
#pragma unroll
    for (int kc = 0; kc < 2; ++kc) ap[kc] = *(const s8v*)&ps[w * 16 + lrow][kc * 32 + lquad * 8];
#pragma unroll
    for (int nt = 0; nt < 4; ++nt)
#pragma unroll
      for (int kc = 0; kc < 2; ++kc) {
        s8v bv = *(const s8v*)&vts[nt * 16 + lrow][kc * 32 + lquad * 8];
        oc[nt] = __builtin_amdgcn_mfma_f32_16x16x32_bf16(ap[kc], bv, oc[nt], 0, 0, 0);
      }
  }
#pragma unroll
  for (int nt = 0; nt < 4; ++nt) {
    int col = h * 64 + nt * 16 + lrow;
#pragma unroll
    for (int j = 0; j < 4; ++j) {
      int r = w * 16 + lquad * 4 + j;
      if (r <= s) o[(soff + r) * 512 + col] = f2bf(oc[nt][j]);
    }
  }
}

// ---------------------------------------------------------------------------
// Last-layer attention: single query row per sequence. Block per (h, seq).
// kvb row = [K(512) | V(512)], ld 1024.
// ---------------------------------------------------------------------------
__global__ __launch_bounds__(64) void k_attn_last(const u16* __restrict__ qb, const u16* __restrict__ kvb,
                                                  u16* __restrict__ attl, int sbase, size_t row0) {
  const int h = blockIdx.x;            // 0..7
  const int r = blockIdx.y;            // sl*32 + b
  const int sl = r >> 5, b = r & 31;
  const int s = sbase + sl;
  const size_t soff = seqoff(s, b) - row0;
  const int lane = threadIdx.x;
  __shared__ float qsm[64], ps[64];
  qsm[lane] = bf2f(qb[(size_t)r * 512 + h * 64 + lane]);
  __syncthreads();
  float sc = -3.0e38f;
  if (lane <= s) {
    const u16* kp = kvb + (soff + lane) * 1024 + h * 64;
    float acc = 0.f;
#pragma unroll
    for (int d = 0; d < 64; d += 8) {
      float kv[8]; load8bf(kp + d, kv);
#pragma unroll
      for (int i = 0; i < 8; ++i) acc += qsm[d + i] * kv[i];
    }
    sc = acc * 0.125f;
  }
  float mx = sc;
#pragma unroll
  for (int m = 1; m < 64; m <<= 1) mx = fmaxf(mx, __shfl_xor(mx, m));
  float e = (lane <= s) ? __expf(sc - mx) : 0.f;
  float sum = e;
#pragma unroll
  for (int m = 1; m < 64; m <<= 1) sum += __shfl_xor(sum, m);
  ps[lane] = e / sum;
  __syncthreads();
  float acc = 0.f;
  for (int k = 0; k <= s; ++k)
    acc += ps[k] * bf2f(kvb[(soff + k) * 1024 + 512 + h * 64 + lane]);
  attl[(size_t)r * 512 + h * 64 + lane] = f2bf(acc);
}

// ---------------------------------------------------------------------------
// Residual + LN (layers 0..6). One wave per 512-row. CA via row->seq map.
// ---------------------------------------------------------------------------
template<int HAS2>
__global__ __launch_bounds__(256) void k_ln(u16* __restrict__ hb, const u16* __restrict__ tmpb,
                                            const u16* __restrict__ cab, const int* __restrict__ map,
                                            size_t row0,
                                            const float* __restrict__ g1, const float* __restrict__ b1,
                                            const float* __restrict__ g2, const float* __restrict__ b2) {
  const int row = blockIdx.x * 4 + (threadIdx.x >> 6);
  const int lane = threadIdx.x & 63;
  const size_t off = (size_t)row * 512 + lane * 8;
  float hv[8], tv[8], t[8];
  load8bf(hb + off, hv); load8bf(tmpb + off, tv);
  float s = 0.f, ss = 0.f;
#pragma unroll
  for (int i = 0; i < 8; ++i) { t[i] = hv[i] + tv[i]; s += t[i]; ss += t[i] * t[i]; }
#pragma unroll
  for (int m = 1; m < 64; m <<= 1) { s += __shfl_xor(s, m); ss += __shfl_xor(ss, m); }
  float mean = s * (1.f / 512.f);
  float inv = 1.f / sqrtf(ss * (1.f / 512.f) - mean * mean + 1e-5f);
  float gv[8], bv[8];
  *(float4*)&gv[0] = *(const float4*)(g1 + lane * 8); *(float4*)&gv[4] = *(const float4*)(g1 + lane * 8 + 4);
  *(float4*)&bv[0] = *(const float4*)(b1 + lane * 8); *(float4*)&bv[4] = *(const float4*)(b1 + lane * 8 + 4);
  if (HAS2) {
    const int seq = map[row0 + row];
    float cv[8]; load8bf(cab + (size_t)seq * 512 + lane * 8, cv);
    float s2 = 0.f, ss2 = 0.f;
#pragma unroll
    for (int i = 0; i < 8; ++i) { float n = (t[i] - mean) * inv * gv[i] + bv[i] + cv[i]; t[i] = n; s2 += n; ss2 += n * n; }
#pragma unroll
    for (int m = 1; m < 64; m <<= 1) { s2 += __shfl_xor(s2, m); ss2 += __shfl_xor(ss2, m); }
    float mean2 = s2 * (1.f / 512.f);
    float inv2 = 1.f / sqrtf(ss2 * (1.f / 512.f) - mean2 * mean2 + 1e-5f);
    float g2v[8], b2v[8];
    *(float4*)&g2v[0] = *(const float4*)(g2 + lane * 8); *(float4*)&g2v[4] = *(const float4*)(g2 + lane * 8 + 4);
    *(float4*)&b2v[0] = *(const float4*)(b2 + lane * 8); *(float4*)&b2v[4] = *(const float4*)(b2 + lane * 8 + 4);
#pragma unroll
    for (int i = 0; i < 8; ++i) t[i] = (t[i] - mean2) * inv2 * g2v[i] + b2v[i];
  } else {
#pragma unroll
    for (int i = 0; i < 8; ++i) t[i] = (t[i] - mean) * inv * gv[i] + bv[i];
  }
  store8bf(hb + off, t);
}

// ---------------------------------------------------------------------------
// Residual + LN for the gathered last rows (layer 7). seq computed directly.
// ---------------------------------------------------------------------------
template<int HAS2>
__global__ __launch_bounds__(256) void k_ln_last(u16* __restrict__ gl, const u16* __restrict__ tmpl,
                                                 const u16* __restrict__ cab, int sbase,
                                                 const float* __restrict__ g1, const float* __restrict__ b1,
                                                 const float* __restrict__ g2, const float* __restrict__ b2) {
  const int row = blockIdx.x * 4 + (threadIdx.x >> 6);
  const int lane = threadIdx.x & 63;
  const size_t off = (size_t)row * 512 + lane * 8;
  float hv[8], tv[8], t[8];
  load8bf(gl + off, hv); load8bf(tmpl + off, tv);
  float s = 0.f, ss = 0.f;
#pragma unroll
  for (int i = 0; i < 8; ++i) { t[i] = hv[i] + tv[i]; s += t[i]; ss += t[i] * t[i]; }
#pragma unroll
  for (int m = 1; m < 64; m <<= 1) { s += __shfl_xor(s, m); ss += __shfl_xor(ss, m); }
  float mean = s * (1.f / 512.f);
  float inv = 1.f / sqrtf(ss * (1.f / 512.f) - mean * mean + 1e-5f);
  float gv[8], bv[8];
  *(float4*)&gv[0] = *(const float4*)(g1 + lane * 8); *(float4*)&gv[4] = *(const float4*)(g1 + lane * 8 + 4);
  *(float4*)&bv[0] = *(const float4*)(b1 + lane * 8); *(float4*)&bv[4] = *(const float4*)(b1 + lane * 8 + 4);
  if (HAS2) {
    const int seq = (sbase + (row >> 5)) * 32 + (row & 31);
    float cv[8]; load8bf(cab + (size_t)seq * 512 + lane * 8, cv);
    float s2 = 0.f, ss2 = 0.f;
#pragma unroll
    for (int i = 0; i < 8; ++i) { float n = (t[i] - mean) * inv * gv[i] + bv[i] + cv[i]; t[i] = n; s2 += n; ss2 += n * n; }
#pragma unroll
    for (int m = 1; m < 64; m <<= 1) { s2 += __shfl_xor(s2, m); ss2 += __shfl_xor(ss2, m); }
    float mean2 = s2 * (1.f / 512.f);
    float inv2 = 1.f / sqrtf(ss2 * (1.f / 512.f) - mean2 * mean2 + 1e-5f);
    float g2v[8], b2v[8];
    *(float4*)&g2v[0] = *(const float4*)(g2 + lane * 8); *(float4*)&g2v[4] = *(const float4*)(g2 + lane * 8 + 4);
    *(float4*)&b2v[0] = *(const float4*)(b2 + lane * 8); *(float4*)&b2v[4] = *(const float4*)(b2 + lane * 8 + 4);
#pragma unroll
    for (int i = 0; i < 8; ++i) t[i] = (t[i] - mean2) * inv2 * g2v[i] + b2v[i];
  } else {
#pragma unroll
    for (int i = 0; i < 8; ++i) t[i] = (t[i] - mean) * inv * gv[i] + bv[i];
  }
  store8bf(gl + off, t);
}

// ---------------------------------------------------------------------------
// ctx0[b,l,:] = x_full[b,l] @ W_in + b_in + PE[l]  (4 independent FMA chains)
// ---------------------------------------------------------------------------
__global__ __launch_bounds__(256) void k_ctx(const float* __restrict__ x, const float* __restrict__ W_in,
                                             const float* __restrict__ b_in, u16* __restrict__ ctx0) {
  const int e = blockIdx.x * 256 + threadIdx.x;   // over B*L*D = 1M
  const int d = e & 511, l = (e >> 9) & 63, b = e >> 15;
  float acc = b_in[d];
  if (l > 0) {
    const float* xr = x + (size_t)(b * 64 + l - 1) * 32;
    float a0 = 0.f, a1 = 0.f, a2 = 0.f, a3 = 0.f;
#pragma unroll
    for (int z = 0; z < 32; z += 4) {
      a0 += xr[z + 0] * W_in[(z + 0) * 512 + d];
      a1 += xr[z + 1] * W_in[(z + 1) * 512 + d];
      a2 += xr[z + 2] * W_in[(z + 2) * 512 + d];
      a3 += xr[z + 3] * W_in[(z + 3) * 512 + d];
    }
    acc += (a0 + a1) + (a2 + a3);
  }
  const float dv = __expf(-9.210340371976184f * (float)(d & ~1) * (1.f / 512.f));
  const float ang = (float)l * dv;
  acc += (d & 1) ? cosf(ang) : sinf(ang);
  ctx0[(size_t)e] = f2bf(acc);
}

// ---------------------------------------------------------------------------
__global__ __launch_bounds__(64) void k_map(int* __restrict__ map) {
  const int seq = blockIdx.x;           // s*32 + b
  const int s = seq >> 5, b = seq & 31;
  const int l = threadIdx.x;
  if (l <= s) map[seqoff(s, b) + l] = seq;
}

// ---------------------------------------------------------------------------
__global__ __launch_bounds__(256) void k_rep(const u16* __restrict__ ctx0, u16* __restrict__ hb,
                                             int sbase, size_t row0) {
  const int sl = blockIdx.x >> 5, b = blockIdx.x & 31;
  const int s = sbase + sl;
  const size_t dst0 = seqoff(s, b) - row0;
  const int tid = threadIdx.x;
  for (int idx = tid; idx < (s + 1) * 64; idx += 256) {
    const int l = idx >> 6, d8 = idx & 63;
    *(uint4*)(hb + (dst0 + l) * 512 + d8 * 8) =
        *(const uint4*)(ctx0 + ((size_t)(b * 64 + l) * 512) + d8 * 8);
  }
}

// ---------------------------------------------------------------------------
// Gather last valid row of each sequence into a compact buffer.
// ---------------------------------------------------------------------------
__global__ __launch_bounds__(64) void k_gather(const u16* __restrict__ hb, u16* __restrict__ gl,
                                               int sbase, size_t row0) {
  const int r = blockIdx.x; const int sl = r >> 5, b = r & 31; const int s = sbase + sl;
  const size_t src = (seqoff(s, b) - row0 + s) * 512;
  const int lane = threadIdx.x;
  *(uint4*)(gl + (size_t)r * 512 + lane * 8) = *(const uint4*)(hb + src + lane * 8);
}

// ---------------------------------------------------------------------------
// VQ nearest-neighbor + mem_h = codebook[kmin] @ W_in + b_in.
// 256 blocks x 8 tokens; codebook streamed once per block via LDS tiles of
// 128 codes (coalesced flat float4 copies). Distances exact fp32 (x-c)^2 in
// 4 chains; argmin as packed (bits(d2)<<32)|idx u64 (first-min tiebreak).
// ---------------------------------------------------------------------------
__global__ __launch_bounds__(256) void k_vq(const float* __restrict__ x, const float* __restrict__ cb,
                                            const float* __restrict__ W_in, const float* __restrict__ b_in,
                                            u16* __restrict__ memh) {
  __shared__ float cs[128 * 36];            // code tile, pad 36 floats (16B-aligned rows)
  __shared__ float xs[8][33];
  const int tid = threadIdx.x;
  const int g = tid >> 5, u = tid & 31;     // token group (0..7), lane-in-group (0..31)
  const int tok = blockIdx.x * 8 + g;       // s*32 + b
  const int s = tok >> 5, b = tok & 31;
  xs[g][u] = x[(size_t)(b * 64 + s) * 32 + u];  // mem token = x[b, s]
  __syncthreads();
  float xr[32];
#pragma unroll
  for (int i = 0; i < 32; ++i) xr[i] = xs[g][i];
  unsigned long long bk = ~0ull;
  for (int tile = 0; tile < 64; ++tile) {
    __syncthreads();
    const float4* src = (const float4*)(cb + (size_t)tile * 128 * 32);
#pragma unroll
    for (int k = 0; k < 4; ++k) {           // 1024 float4s / 256 threads
      int f4 = k * 256 + tid;
      int c = f4 >> 3, z = (f4 & 7) * 4;
      *(float4*)&cs[c * 36 + z] = src[f4];
    }
    __syncthreads();
#pragma unroll
    for (int j = 0; j < 4; ++j) {
      int c = j * 32 + u;
      const float* cp = &cs[c * 36];
      float d0 = 0.f, d1 = 0.f, d2 = 0.f, d3 = 0.f;
#pragma unroll
      for (int z4 = 0; z4 < 8; ++z4) {
        float4 cv = *(const float4*)(cp + z4 * 4);
        float t0 = xr[z4 * 4 + 0] - cv.x, t1 = xr[z4 * 4 + 1] - cv.y;
        float t2 = xr[z4 * 4 + 2] - cv.z, t3 = xr[z4 * 4 + 3] - cv.w;
        d0 += t0 * t0; d1 += t1 * t1; d2 += t2 * t2; d3 += t3 * t3;
      }
      float d = (d0 + d1) + (d2 + d3);
      unsigned db; memcpy(&db, &d, 4);      // d >= 0 -> bits order == float order
      unsigned long long key = ((unsigned long long)db << 32) | (unsigned)(tile * 128 + c);
      bk = key < bk ? key : bk;
    }
  }
#pragma unroll
  for (int m = 1; m < 32; m <<= 1) {        // butterfly min within the 32-lane group
    unsigned long long o = __shfl_xor(bk, m);
    bk = o < bk ? o : bk;
  }
  const int kmin = (int)(bk & 0xffffffffu);
  float cw[32];
#pragma unroll
  for (int z = 0; z < 32; ++z) cw[z] = cb[(size_t)kmin * 32 + z];
  for (int k = 0; k < 16; ++k) {
    int o = u + 32 * k;
    float a = b_in[o];
#pragma unroll
    for (int z = 0; z < 32; ++z) a += cw[z] * W_in[z * 512 + o];
    memh[(size_t)tok * 512 + o] = f2bf(a);
  }
}

// ---------------------------------------------------------------------------
// Final: out[b,s,:] = LN(gl[r,:]) @ W_out + b_out. Block per seq r = sl*32+b.
// ---------------------------------------------------------------------------
__global__ __launch_bounds__(64) void k_final(const u16* __restrict__ gl, const float* __restrict__ g,
                                              const float* __restrict__ bta, const float* __restrict__ Wout,
                                              const float* __restrict__ bout, float* __restrict__ out,
                                              int sbase) {
  const int blk = blockIdx.x;            // sl*32 + b
  const int s = sbase + (blk >> 5), b = blk & 31;
  const int lane = threadIdx.x;
  __shared__ float ns[512];
  const size_t roff = (size_t)blk * 512;
  float v[8]; load8bf(gl + roff + lane * 8, v);
  float sm = 0.f, ssm = 0.f;
#pragma unroll
  for (int i = 0; i < 8; ++i) { sm += v[i]; ssm += v[i] * v[i]; }
#pragma unroll
  for (int m = 1; m < 64; m <<= 1) { sm += __shfl_xor(sm, m); ssm += __shfl_xor(ssm, m); }
  float mean = sm * (1.f / 512.f);
  float inv = 1.f / sqrtf(ssm * (1.f / 512.f) - mean * mean + 1e-5f);
#pragma unroll
  for (int i = 0; i < 8; ++i) ns[lane * 8 + i] = (v[i] - mean) * inv * g[lane * 8 + i] + bta[lane * 8 + i];
  __syncthreads();
  const int col = lane & 31, half = lane >> 5;
  float a = 0.f;
  for (int k = half * 256; k < half * 256 + 256; ++k) a += ns[k] * Wout[(size_t)k * 32 + col];
  a += __shfl_xor(a, 32);
  if (lane < 32) out[((size_t)b * 64 + s) * 32 + col] = a + bout[col];
}

// ---------------------------------------------------------------------------
// Transpose + fp32->bf16 cast of weights: dst[l][c][r] = src[l][r][col0 + c]
// ---------------------------------------------------------------------------
__global__ void k_tcast(const float* __restrict__ src, u16* __restrict__ dst, int R, int C, int ld, int col0) {
  const int l = blockIdx.z;
  src += (size_t)l * R * ld;
  dst += (size_t)l * R * C;
  __shared__ float t[32][33];
  const int c0 = blockIdx.x * 32, r0 = blockIdx.y * 32;
  const int tx = threadIdx.x, ty = threadIdx.y;
#pragma unroll
  for (int k = 0; k < 4; ++k)
    t[ty + 8 * k][tx] = src[(size_t)(r0 + ty + 8 * k) * ld + col0 + c0 + tx];
  __syncthreads();
#pragma unroll
  for (int k = 0; k < 4; ++k)
    dst[(size_t)(c0 + ty + 8 * k) * R + r0 + tx] = f2bf(t[tx][ty + 8 * k]);
}

// ---------------------------------------------------------------------------
extern "C" void kernel_launch(void* const* d_in, const int* in_sizes, int n_in,
                              void* d_out, int out_size, void* d_ws, size_t ws_size,
                              hipStream_t stream) {
  (void)in_sizes; (void)n_in; (void)out_size;
  const float* x    = (const float*)d_in[0];
  const float* cb   = (const float*)d_in[1];
  const float* W_in = (const float*)d_in[2];
  const float* b_in = (const float*)d_in[3];
  const float* saqw = (const float*)d_in[4];
  const float* saqb = (const float*)d_in[5];
  const float* saow = (const float*)d_in[6];
  const float* saob = (const float*)d_in[7];
  const float* caqw = (const float*)d_in[8];
  const float* caqb = (const float*)d_in[9];
  const float* caow = (const float*)d_in[10];
  const float* caob = (const float*)d_in[11];
  const float* f1w  = (const float*)d_in[12];
  const float* f1b  = (const float*)d_in[13];
  const float* f2w  = (const float*)d_in[14];
  const float* f2b  = (const float*)d_in[15];
  const float* l1g  = (const float*)d_in[16];
  const float* l1b  = (const float*)d_in[17];
  const float* l2g  = (const float*)d_in[18];
  const float* l2b  = (const float*)d_in[19];
  const float* l3g  = (const float*)d_in[20];
  const float* l3b  = (const float*)d_in[21];
  const float* lng  = (const float*)d_in[22];
  const float* lnb  = (const float*)d_in[23];
  const float* Wout = (const float*)d_in[24];
  const float* bout = (const float*)d_in[25];
  float* out = (float*)d_out;

  // -------------------- workspace layout (u16 elements) --------------------
  u16* ws = (u16*)d_ws;
  size_t off = 0;
  auto alloc = [&](size_t n) { u16* p = ws + off; off += n; return p; };
  // persistent region (~97 MB)
  u16* ctx0  = alloc((size_t)32 * 64 * 512);          // 1,048,576
  u16* cabuf = alloc((size_t)NLAY * SB * 512);        // 8,388,608
  u16* memh  = alloc((size_t)SB * 512);               // 1,048,576
  u16* tmpv8 = alloc((size_t)NLAY * SB * 512);        // 8,388,608 (CA mid; reused as last-layer bufs)
  u16* wqkvT = alloc((size_t)NLAY * 1536 * 512);      // 6,291,456
  u16* woutT = alloc((size_t)NLAY * 512 * 512);       // 2,097,152
  u16* wf1T  = alloc((size_t)NLAY * 2048 * 512);      // 8,388,608
  u16* wf2T  = alloc((size_t)NLAY * 512 * 2048);      // 8,388,608
  u16* wcavT = alloc((size_t)NLAY * 512 * 512);       // 2,097,152
  u16* wcaoT = alloc((size_t)NLAY * 512 * 512);       // 2,097,152
  int* rowmap = (int*)alloc(RAGG * 2);                // row -> seq id

  // last-layer buffers alias tmpv8 (dead after CA precompute): need 8M el
  u16* glast = tmpv8;                    // [2048][512]
  u16* qb    = tmpv8 + 1048576;          // [2048][512]
  u16* attl  = tmpv8 + 2 * 1048576;      // [2048][512]
  u16* tmpl  = tmpv8 + 3 * 1048576;      // [2048][512]
  u16* midl  = tmpv8 + 4 * 1048576;      // [2048][2048]

  // ragged chunk row budget (3072 bf16 per row across hb/regA/tmpb)
  size_t avail = ws_size / 2 > off ? ws_size / 2 - off : 0;
  size_t Ralloc = avail / 3072;
  Ralloc = Ralloc / 128 * 128;
  if (Ralloc > RAGG) Ralloc = RAGG;

  u16* hb   = alloc(Ralloc * 512);    // residual stream for the chunk
  u16* regA = alloc(Ralloc * 2048);   // qkv (1536)+attn (512) / ffn-mid (2048) / kv (1024)
  u16* tmpb = alloc(Ralloc * 512);    // GEMM output scratch
  u16* qkvb = regA;                   // [rows][1536]
  u16* attb = regA + Ralloc * 1536;   // [rows][512]
  u16* midb = regA;                   // [rows][2048]
  u16* kvb  = regA;                   // [rows][1024] (layer 7)

  // -------------------- weight transpose + cast (every launch) -------------
  dim3 tb(32, 8);
  k_tcast<<<dim3(48, 16, 8), tb, 0, stream>>>(saqw, wqkvT, 512, 1536, 1536, 0);
  k_tcast<<<dim3(16, 16, 8), tb, 0, stream>>>(saow, woutT, 512, 512, 512, 0);
  k_tcast<<<dim3(64, 16, 8), tb, 0, stream>>>(f1w, wf1T, 512, 2048, 2048, 0);
  k_tcast<<<dim3(16, 64, 8), tb, 0, stream>>>(f2w, wf2T, 2048, 512, 512, 0);
  k_tcast<<<dim3(16, 16, 8), tb, 0, stream>>>(caqw, wcavT, 512, 512, 1536, 1024);  // v-slice of ca qkv
  k_tcast<<<dim3(16, 16, 8), tb, 0, stream>>>(caow, wcaoT, 512, 512, 512, 0);

  k_ctx<<<4096, 256, 0, stream>>>(x, W_in, b_in, ctx0);
  k_vq<<<256, 256, 0, stream>>>(x, cb, W_in, b_in, memh);
  k_map<<<2048, 64, 0, stream>>>(rowmap);

  // Cross-attention collapses to per-(s,b) constants; batched over layers.
  gemm_ca<<<dim3(4, 16, 8), 256, 0, stream>>>(memh, wcavT, caqb + 1024, tmpv8,
                                              0, (size_t)512 * 512, 1536, (size_t)SB * 512);
  gemm_ca<<<dim3(4, 16, 8), 256, 0, stream>>>(tmpv8, wcaoT, caob, cabuf,
                                              (size_t)SB * 512, (size_t)512 * 512, 512, (size_t)SB * 512);

  // -------------------- main decoder, ragged chunks over steps --------------
  int sstart = 0;
  while (sstart < 64) {
    int send = sstart;
    size_t rows = 0;
    while (send < 64) {
      size_t nr = rows + (size_t)32 * (send + 1);
      size_t pr = (nr + 127) / 128 * 128;
      if (pr > Ralloc && send > sstart) break;
      rows = nr; ++send;
      if (pr > Ralloc) break;
    }
    const size_t row0 = (size_t)16 * sstart * (sstart + 1);
    const size_t rows_pad = (rows + 127) / 128 * 128;
    const int mg = (int)(rows_pad / 128);
    const int ns = send - sstart;
    const int nseq = ns * 32;
    const int nseqp = (nseq + 127) / 128 * 128;

    k_rep<<<nseq, 256, 0, stream>>>(ctx0, hb, sstart, row0);
    for (int l = 0; l < NLAY - 1; ++l) {
      gemm_bt<0><<<dim3(12, mg), 256, 0, stream>>>(hb, wqkvT + (size_t)l * 1536 * 512,
                                                   saqb + (size_t)l * 1536, qkvb, 1536, 512);
      k_attn<<<dim3(8, 32, ns), 256, 0, stream>>>(qkvb, attb, sstart, row0);
      gemm_bt<0><<<dim3(4, mg), 256, 0, stream>>>(attb, woutT + (size_t)l * 512 * 512,
                                                  saob + (size_t)l * 512, tmpb, 512, 512);
      k_ln<1><<<(int)(rows / 4), 256, 0, stream>>>(hb, tmpb, cabuf + (size_t)l * SB * 512,
                                                   rowmap, row0,
                                                   l1g + l * 512, l1b + l * 512, l2g + l * 512, l2b + l * 512);
      gemm_bt<1><<<dim3(16, mg), 256, 0, stream>>>(hb, wf1T + (size_t)l * 2048 * 512,
                                                   f1b + (size_t)l * 2048, midb, 2048, 512);
      gemm_bt<0><<<dim3(4, mg), 256, 0, stream>>>(midb, wf2T + (size_t)l * 512 * 2048,
                                                  f2b + (size_t)l * 512, tmpb, 512, 2048);
      k_ln<0><<<(int)(rows / 4), 256, 0, stream>>>(hb, tmpb, nullptr, rowmap, row0,
                                                   l3g + l * 512, l3b + l * 512, nullptr, nullptr);
    }
    // ---- layer 7: only row l=s of each sequence reaches the output ----
    {
      const size_t l7q = (size_t)7 * 1536 * 512;
      k_gather<<<nseq, 64, 0, stream>>>(hb, glast, sstart, row0);
      gemm_bt<0><<<dim3(8, mg), 256, 0, stream>>>(hb, wqkvT + l7q + (size_t)512 * 512,
                                                  saqb + 7 * 1536 + 512, kvb, 1024, 512);
      gemm_bt<0><<<dim3(4, nseqp / 128), 256, 0, stream>>>(glast, wqkvT + l7q,
                                                           saqb + 7 * 1536, qb, 512, 512);
      k_attn_last<<<dim3(8, nseq), 64, 0, stream>>>(qb, kvb, attl, sstart, row0);
      gemm_bt<0><<<dim3(4, nseqp / 128), 256, 0, stream>>>(attl, woutT + (size_t)7 * 512 * 512,
                                                           saob + 7 * 512, tmpl, 512, 512);
      k_ln_last<1><<<nseq / 4, 256, 0, stream>>>(glast, tmpl, cabuf + (size_t)7 * SB * 512, sstart,
                                                 l1g + 7 * 512, l1b + 7 * 512, l2g + 7 * 512, l2b + 7 * 512);
      gemm_bt<1><<<dim3(16, nseqp / 128), 256, 0, stream>>>(glast, wf1T + (size_t)7 * 2048 * 512,
                                                            f1b + (size_t)7 * 2048, midl, 2048, 512);
      gemm_bt<0><<<dim3(4, nseqp / 128), 256, 0, stream>>>(midl, wf2T + (size_t)7 * 512 * 2048,
                                                           f2b + 7 * 512, tmpl, 512, 2048);
      k_ln_last<0><<<nseq / 4, 256, 0, stream>>>(glast, tmpl, nullptr, sstart,
                                                 l3g + 7 * 512, l3b + 7 * 512, nullptr, nullptr);
      k_final<<<nseq, 64, 0, stream>>>(glast, lng, lnb, Wout, bout, out, sstart);
    }
    sstart = send;
  }
}